// Round 1
// baseline (553.334 us; speedup 1.0000x reference)
//
#include <hip/hip_runtime.h>

using u16 = unsigned short;
using short8 = __attribute__((ext_vector_type(8))) short;
using f32x4 = __attribute__((ext_vector_type(4))) float;

#define NTOK 4096
#define CDIM 768
#define QKVD 2304
#define NHEAD 12

__device__ __forceinline__ u16 f2bf(float f) {
  unsigned u = __float_as_uint(f);
  u += 0x7FFFu + ((u >> 16) & 1u);
  return (u16)(u >> 16);
}

__device__ __forceinline__ void gload_lds16(const void* g, void* l) {
  __builtin_amdgcn_global_load_lds(
      (__attribute__((address_space(1))) void*)g,
      (__attribute__((address_space(3))) void*)l, 16u, 0, 0u);
}

__device__ __forceinline__ float gelu_exact(float z) {
  return 0.5f * z * (1.0f + erff(z * 0.70710678118654752f));
}

// ---------------- edge mask: pool 16x16 blocks of alpha_hint ----------------
__global__ __launch_bounds__(256) void pool_hint_kernel(
    const float* __restrict__ ah, float* __restrict__ hint)
{
  const int bid = blockIdx.x;            // B*64 blocks: (b, cellrow)
  const int b = bid >> 6, cr = bid & 63;
  const int t = threadIdx.x;
  const float* base = ah + ((size_t)b * 1024 + (size_t)cr * 16) * 1024;
  float s = 0.f;
#pragma unroll
  for (int pr = 0; pr < 16; ++pr) {
    float4 v = *(const float4*)(base + (size_t)pr * 1024 + t * 4);
    s += v.x + v.y + v.z + v.w;
  }
  s += __shfl_xor(s, 1);
  s += __shfl_xor(s, 2);
  if ((t & 3) == 0)
    hint[b * NTOK + cr * 64 + (t >> 2)] = s * (1.f / 256.f);
}

__global__ __launch_bounds__(1024) void finalize_edge_kernel(
    const float* __restrict__ hint, int* __restrict__ edge,
    int* __restrict__ qidx, int* __restrict__ ecnt)
{
  const int b = blockIdx.x, t = threadIdx.x;
  __shared__ int wsum[16];
  __shared__ int scnt;
  __shared__ int stot;
  int bits[4]; int s = 0;
#pragma unroll
  for (int j = 0; j < 4; ++j) {
    float h = hint[b * NTOK + t * 4 + j];
    bits[j] = (h > 0.02f && h < 0.98f) ? 1 : 0;
    s += bits[j];
    qidx[b * NTOK + t * 4 + j] = -1;
  }
  int sw = s;
#pragma unroll
  for (int d = 1; d < 64; d <<= 1) sw += __shfl_xor(sw, d);
  const int l = t & 63, w = t >> 6;
  if (l == 0) wsum[w] = sw;
  if (t == 0) scnt = 0;
  __syncthreads();
  if (t == 0) { int a = 0; for (int i = 0; i < 16; ++i) a += wsum[i]; stot = a; }
  __syncthreads();
  const int cnt = stot;
  const bool fb = cnt < 64;     // fallback: route everything to attention
#pragma unroll
  for (int j = 0; j < 4; ++j) {
    int e = fb ? 1 : bits[j];
    edge[b * NTOK + t * 4 + j] = e;
    if (e) {
      int p = atomicAdd(&scnt, 1);
      qidx[b * NTOK + p] = t * 4 + j;
    }
  }
  if (t == 0) ecnt[b] = fb ? 0 : (NTOK - cnt);   // easy-token count
}

// ---------------- LayerNorm (writes ln bf16) + x->bf16 ----------------
__global__ __launch_bounds__(256) void ln_kernel(
    const float* __restrict__ x, const float* __restrict__ gam,
    const float* __restrict__ bet, u16* __restrict__ lnb, u16* __restrict__ xb)
{
  const int row = blockIdx.x, t = threadIdx.x;
  const float* xr = x + (size_t)row * CDIM;
  float v[3];
#pragma unroll
  for (int j = 0; j < 3; ++j) v[j] = xr[t + j * 256];
  float s = v[0] + v[1] + v[2];
  float ss = v[0] * v[0] + v[1] * v[1] + v[2] * v[2];
#pragma unroll
  for (int d = 1; d < 64; d <<= 1) { s += __shfl_xor(s, d); ss += __shfl_xor(ss, d); }
  __shared__ float red[8];
  const int l = t & 63, w = t >> 6;
  if (l == 0) { red[w * 2] = s; red[w * 2 + 1] = ss; }
  __syncthreads();
  s = red[0] + red[2] + red[4] + red[6];
  ss = red[1] + red[3] + red[5] + red[7];
  const float mu = s * (1.f / 768.f);
  const float rstd = rsqrtf(ss * (1.f / 768.f) - mu * mu + 1e-5f);
#pragma unroll
  for (int j = 0; j < 3; ++j) {
    const int cc = t + j * 256;
    lnb[(size_t)row * CDIM + cc] = f2bf((v[j] - mu) * rstd * gam[cc] + bet[cc]);
    xb[(size_t)row * CDIM + cc] = f2bf(v[j]);
  }
}

// ---------------- fp32 [K,N] -> bf16 [N,K] transpose ----------------
__global__ __launch_bounds__(256) void transpose_kernel(
    const float* __restrict__ in, u16* __restrict__ outp, int K, int N)
{
  __shared__ float tile[32][33];
  const int bx = blockIdx.x, by = blockIdx.y;       // (N/32, K/32)
  const int tx = threadIdx.x & 31, ty = threadIdx.x >> 5;
#pragma unroll
  for (int j = 0; j < 32; j += 8)
    tile[ty + j][tx] = in[(size_t)(by * 32 + ty + j) * N + bx * 32 + tx];
  __syncthreads();
#pragma unroll
  for (int j = 0; j < 32; j += 8)
    outp[(size_t)(bx * 32 + ty + j) * K + by * 32 + tx] = f2bf(tile[tx][ty + j]);
}

// ---------------- bf16 MFMA GEMM: C[M,N] = A[M,K] @ Bt[N,K]^T ----------------
// EPI: 0 = +bias -> bf16 ; 1 = +bias+resid -> f32 ; 2 = gelu(gelu(+bias)) -> bf16 ; 3 = +bias -> f32
template <int EPI>
__global__ __launch_bounds__(256) void gemm_bt(
    const u16* __restrict__ A, const u16* __restrict__ Bt,
    const float* __restrict__ bias, const float* __restrict__ resid,
    void* __restrict__ outp, int M, int N, int K)
{
  __shared__ __align__(16) u16 lA[128 * 32];
  __shared__ __align__(16) u16 lB[128 * 32];
  const int t = threadIdx.x;
  const int l = t & 63, w = t >> 6;
  const int g = l >> 4, c = l & 15;
  const int wr = w >> 1, wc = w & 1;
  const int bm = blockIdx.x, bn = blockIdx.y;

  f32x4 acc[4][4];
#pragma unroll
  for (int i = 0; i < 4; ++i)
#pragma unroll
    for (int j = 0; j < 4; ++j) acc[i][j] = f32x4{0.f, 0.f, 0.f, 0.f};

  const int srow = t >> 2;                      // 0..63
  const int sslot = (t & 3) ^ (srow & 3);       // pre-swizzled source slot
  const u16* gA0 = A + (size_t)(bm * 128 + srow) * K + sslot * 8;
  const u16* gA1 = A + (size_t)(bm * 128 + 64 + srow) * K + sslot * 8;
  const u16* gB0 = Bt + (size_t)(bn * 128 + srow) * K + sslot * 8;
  const u16* gB1 = Bt + (size_t)(bn * 128 + 64 + srow) * K + sslot * 8;
  char* ldA = (char*)lA + w * 1024;
  char* ldB = (char*)lB + w * 1024;

  for (int k0 = 0; k0 < K; k0 += 32) {
    __syncthreads();
    gload_lds16(gA0 + k0, ldA);
    gload_lds16(gA1 + k0, ldA + 4096);
    gload_lds16(gB0 + k0, ldB);
    gload_lds16(gB1 + k0, ldB + 4096);
    __syncthreads();
    short8 af[4], bfr[4];
#pragma unroll
    for (int mi = 0; mi < 4; ++mi) {
      int row = wr * 64 + mi * 16 + c;
      af[mi] = *(const short8*)((const char*)lA + row * 64 + ((g ^ (row & 3)) << 4));
    }
#pragma unroll
    for (int ni = 0; ni < 4; ++ni) {
      int row = wc * 64 + ni * 16 + c;
      bfr[ni] = *(const short8*)((const char*)lB + row * 64 + ((g ^ (row & 3)) << 4));
    }
#pragma unroll
    for (int mi = 0; mi < 4; ++mi)
#pragma unroll
      for (int ni = 0; ni < 4; ++ni)
        acc[mi][ni] = __builtin_amdgcn_mfma_f32_16x16x32_bf16(af[mi], bfr[ni], acc[mi][ni], 0, 0, 0);
  }

#pragma unroll
  for (int mi = 0; mi < 4; ++mi) {
#pragma unroll
    for (int ni = 0; ni < 4; ++ni) {
      const int col = bn * 128 + wc * 64 + ni * 16 + c;
      const float bv = bias[col];
      const int row0 = bm * 128 + wr * 64 + mi * 16 + g * 4;
#pragma unroll
      for (int r = 0; r < 4; ++r) {
        float v = acc[mi][ni][r] + bv;
        const size_t idx = (size_t)(row0 + r) * N + col;
        if constexpr (EPI == 0) {
          ((u16*)outp)[idx] = f2bf(v);
        } else if constexpr (EPI == 1) {
          ((float*)outp)[idx] = v + resid[idx];
        } else if constexpr (EPI == 2) {
          ((u16*)outp)[idx] = f2bf(gelu_exact(gelu_exact(v)));
        } else {
          ((float*)outp)[idx] = v;
        }
      }
    }
  }
}

// ---------------- compacted flash attention over edge tokens ----------------
__global__ __launch_bounds__(256) void flash_kernel(
    const u16* __restrict__ qkv, const int* __restrict__ qidx, u16* __restrict__ o)
{
  const int qt = blockIdx.x;
  const int bh = blockIdx.y;
  const int b = bh / NHEAD, h = bh % NHEAD;
  const int* qx = qidx + b * NTOK;
  if (qx[qt * 128] < 0) return;   // entire query block beyond compact count

  __shared__ __align__(16) u16 lK[64 * 64];      // [key][dim], source-swizzled
  __shared__ __align__(16) u16 lV[64 * 64];      // [dim][key], swizzled
  __shared__ __align__(16) u16 lP[4][32 * 64];   // per-wave P, swizzled

  const int t = threadIdx.x;
  const int l = t & 63, w = t >> 6;
  const int g = l >> 4, c = l & 15;
  const size_t tokbase = (size_t)b * NTOK;

  short8 qf[2][2];
#pragma unroll
  for (int mi = 0; mi < 2; ++mi) {
    int qi = qx[qt * 128 + w * 32 + mi * 16 + c];
    if (qi < 0) qi = 0;
    const u16* qp = qkv + (tokbase + qi) * QKVD + h * 64;
#pragma unroll
    for (int kb = 0; kb < 2; ++kb)
      qf[mi][kb] = *(const short8*)(qp + kb * 32 + g * 8);
  }

  f32x4 oacc[2][4];
  float mrun[2][4], lrun[2][4];
#pragma unroll
  for (int mi = 0; mi < 2; ++mi) {
#pragma unroll
    for (int nd = 0; nd < 4; ++nd) oacc[mi][nd] = f32x4{0.f, 0.f, 0.f, 0.f};
#pragma unroll
    for (int r = 0; r < 4; ++r) { mrun[mi][r] = -1e30f; lrun[mi][r] = 0.f; }
  }

  u16* lPw = lP[w];

  for (int kt = 0; kt < NTOK / 64; ++kt) {
    if (qx[kt * 64] < 0) break;
    __syncthreads();
    // stage K (gathered, swizzled global source -> linear LDS)
#pragma unroll
    for (int j = 0; j < 2; ++j) {
      int seg = j * 256 + t;
      int row = seg >> 3;
      int sl = (seg & 7) ^ (row & 7);
      int ki = qx[kt * 64 + row]; if (ki < 0) ki = 0;
      gload_lds16(qkv + (tokbase + ki) * QKVD + CDIM + h * 64 + sl * 8,
                  (char*)lK + j * 4096 + w * 1024);
    }
    // stage V transposed (gathered) with swizzle
    {
      int vi = qx[kt * 64 + l]; if (vi < 0) vi = 0;
      const u16* vg = qkv + (tokbase + vi) * QKVD + 2 * CDIM + h * 64 + w * 16;
      union { uint4 q[2]; u16 s[16]; } vv;
      vv.q[0] = *(const uint4*)(vg);
      vv.q[1] = *(const uint4*)(vg + 8);
#pragma unroll
      for (int jj = 0; jj < 16; ++jj) {
        int d = w * 16 + jj;
        *(u16*)((char*)lV + d * 128 + ((l * 2) ^ ((d & 7) << 4))) = vv.s[jj];
      }
    }
    __syncthreads();

    // S = Q K^T
    short8 kf[4][2];
#pragma unroll
    for (int ni = 0; ni < 4; ++ni) {
      int row = ni * 16 + c;
#pragma unroll
      for (int kb = 0; kb < 2; ++kb)
        kf[ni][kb] = *(const short8*)((const char*)lK + row * 128 + (((kb * 4 + g) ^ (row & 7)) << 4));
    }
    f32x4 s[2][4];
#pragma unroll
    for (int mi = 0; mi < 2; ++mi)
#pragma unroll
      for (int ni = 0; ni < 4; ++ni) {
        f32x4 sv = f32x4{0.f, 0.f, 0.f, 0.f};
        sv = __builtin_amdgcn_mfma_f32_16x16x32_bf16(qf[mi][0], kf[ni][0], sv, 0, 0, 0);
        sv = __builtin_amdgcn_mfma_f32_16x16x32_bf16(qf[mi][1], kf[ni][1], sv, 0, 0, 0);
        s[mi][ni] = sv;
      }

    float emask[4];
#pragma unroll
    for (int ni = 0; ni < 4; ++ni)
      emask[ni] = (qx[kt * 64 + ni * 16 + c] >= 0) ? 0.f : -1e9f;

#pragma unroll
    for (int mi = 0; mi < 2; ++mi) {
      float mx[4];
#pragma unroll
      for (int r = 0; r < 4; ++r) {
        float a0 = s[mi][0][r] * 0.125f + emask[0];
        float a1 = s[mi][1][r] * 0.125f + emask[1];
        float a2 = s[mi][2][r] * 0.125f + emask[2];
        float a3 = s[mi][3][r] * 0.125f + emask[3];
        s[mi][0][r] = a0; s[mi][1][r] = a1; s[mi][2][r] = a2; s[mi][3][r] = a3;
        mx[r] = fmaxf(fmaxf(a0, a1), fmaxf(a2, a3));
      }
#pragma unroll
      for (int r = 0; r < 4; ++r)
#pragma unroll
        for (int d = 1; d < 16; d <<= 1)
          mx[r] = fmaxf(mx[r], __shfl_xor(mx[r], d));

      float alpha[4], rs[4];
#pragma unroll
      for (int r = 0; r < 4; ++r) {
        float mnew = fmaxf(mrun[mi][r], mx[r]);
        alpha[r] = __expf(mrun[mi][r] - mnew);
        mrun[mi][r] = mnew;
        float accp = 0.f;
        const int prow = mi * 16 + g * 4 + r;
#pragma unroll
        for (int ni = 0; ni < 4; ++ni) {
          float p = __expf(s[mi][ni][r] - mnew);
          accp += p;
          *(u16*)((char*)lPw + prow * 128 + (((ni * 16 + c) * 2) ^ ((prow & 7) << 4))) = f2bf(p);
        }
        rs[r] = accp;
      }
#pragma unroll
      for (int r = 0; r < 4; ++r)
#pragma unroll
        for (int d = 1; d < 16; d <<= 1) rs[r] += __shfl_xor(rs[r], d);
#pragma unroll
      for (int r = 0; r < 4; ++r) {
        lrun[mi][r] = lrun[mi][r] * alpha[r] + rs[r];
#pragma unroll
        for (int nd = 0; nd < 4; ++nd) oacc[mi][nd][r] *= alpha[r];
      }
    }

    // O += P V
#pragma unroll
    for (int kb = 0; kb < 2; ++kb) {
      short8 pa[2], vf[4];
#pragma unroll
      for (int mi = 0; mi < 2; ++mi) {
        int prow = mi * 16 + c;
        pa[mi] = *(const short8*)((const char*)lPw + prow * 128 + (((kb * 4 + g) ^ (prow & 7)) << 4));
      }
#pragma unroll
      for (int nd = 0; nd < 4; ++nd) {
        int vrow = nd * 16 + c;
        vf[nd] = *(const short8*)((const char*)lV + vrow * 128 + (((kb * 4 + g) ^ (vrow & 7)) << 4));
      }
#pragma unroll
      for (int mi = 0; mi < 2; ++mi)
#pragma unroll
        for (int nd = 0; nd < 4; ++nd)
          oacc[mi][nd] = __builtin_amdgcn_mfma_f32_16x16x32_bf16(pa[mi], vf[nd], oacc[mi][nd], 0, 0, 0);
    }
  }

  // scatter O back to edge-token rows
#pragma unroll
  for (int mi = 0; mi < 2; ++mi) {
    float inv[4];
#pragma unroll
    for (int r = 0; r < 4; ++r) inv[r] = 1.f / lrun[mi][r];
#pragma unroll
    for (int r = 0; r < 4; ++r) {
      int oi = qx[qt * 128 + w * 32 + mi * 16 + g * 4 + r];
      if (oi >= 0) {
        u16* op = o + (tokbase + oi) * CDIM + h * 64;
#pragma unroll
        for (int nd = 0; nd < 4; ++nd)
          op[nd * 16 + c] = f2bf(oacc[mi][nd][r] * inv[r]);
      }
    }
  }
}

// ---------------- masked mean pool partials ----------------
__global__ __launch_bounds__(256) void pool_partial_kernel(
    const float* __restrict__ h2, const int* __restrict__ edge, float* __restrict__ pooled)
{
  const int bid = blockIdx.x;                 // 96 = b*48 + cg*16 + ts
  const int b = bid / 48, rm = bid % 48;
  const int cg = rm / 16, ts = rm % 16;
  const int ch = cg * 256 + threadIdx.x;
  float s = 0.f;
  for (int tok = ts * 256; tok < ts * 256 + 256; ++tok) {
    if (!edge[b * NTOK + tok])
      s += h2[((size_t)b * NTOK + tok) * CDIM + ch];
  }
  atomicAdd(&pooled[b * CDIM + ch], s);
}

// ---------------- ECA conv(5) + sigmoid ----------------
__global__ void eca_kernel(const float* __restrict__ pooled, const float* __restrict__ w5,
                           const int* __restrict__ ecnt, float* __restrict__ gate)
{
  const int b = blockIdx.x, c = threadIdx.x;
  const float inv = 1.f / fmaxf((float)ecnt[b], 1.f);
  float a = 0.f;
#pragma unroll
  for (int j = 0; j < 5; ++j) {
    int i = c - 2 + j;
    if (i >= 0 && i < CDIM) a += w5[j] * pooled[b * CDIM + i];
  }
  a *= inv;
  gate[b * CDIM + c] = 1.f / (1.f + __expf(-a));
}

// ---------------- final scatter-combine ----------------
__global__ __launch_bounds__(256) void combine_kernel(
    const float* __restrict__ x, const float* __restrict__ attn,
    const float* __restrict__ h2, const float* __restrict__ gate,
    const int* __restrict__ edge, float* __restrict__ out)
{
  const size_t i = ((size_t)blockIdx.x * 256 + threadIdx.x) * 4;
  const int b = (int)(i / ((size_t)NTOK * CDIM));
  const size_t r = i % ((size_t)NTOK * CDIM);
  const int tok = (int)(r / CDIM);
  const int cc = (int)(r % CDIM);
  float4 ov;
  if (edge[b * NTOK + tok]) {
    ov = *(const float4*)(attn + i);
  } else {
    float4 xv = *(const float4*)(x + i);
    float4 hv = *(const float4*)(h2 + i);
    float4 gv = *(const float4*)(gate + b * CDIM + cc);
    ov.x = xv.x + hv.x * gv.x;
    ov.y = xv.y + hv.y * gv.y;
    ov.z = xv.z + hv.z * gv.z;
    ov.w = xv.w + hv.w * gv.w;
  }
  *(float4*)(out + i) = ov;
}

extern "C" void kernel_launch(void* const* d_in, const int* in_sizes, int n_in,
                              void* d_out, int out_size, void* d_ws, size_t ws_size,
                              hipStream_t stream) {
  const float* x      = (const float*)d_in[0];
  const float* ah     = (const float*)d_in[1];
  const float* qkv_w  = (const float*)d_in[2];
  const float* qkv_b  = (const float*)d_in[3];
  const float* proj_w = (const float*)d_in[4];
  const float* proj_b = (const float*)d_in[5];
  const float* ln_g   = (const float*)d_in[6];
  const float* ln_b   = (const float*)d_in[7];
  const float* fc1_w  = (const float*)d_in[8];
  const float* fc1_b  = (const float*)d_in[9];
  const float* fc2_w  = (const float*)d_in[10];
  const float* fc2_b  = (const float*)d_in[11];
  const float* eca_w  = (const float*)d_in[12];
  float* out = (float*)d_out;

  char* ws = (char*)d_ws;
  size_t off = 0;
  auto alloc = [&](size_t bytes) {
    char* p = ws + off;
    off += (bytes + 255) & ~(size_t)255;
    return p;
  };
  float* hint   = (float*)alloc((size_t)2 * NTOK * 4);
  int*   edge   = (int*)alloc((size_t)2 * NTOK * 4);
  int*   qidx   = (int*)alloc((size_t)2 * NTOK * 4);
  int*   ecnt   = (int*)alloc(256);
  u16*   xbf    = (u16*)alloc((size_t)2 * NTOK * CDIM * 2);
  u16*   lnbf   = (u16*)alloc((size_t)2 * NTOK * CDIM * 2);
  u16*   qkvT   = (u16*)alloc((size_t)QKVD * CDIM * 2);
  u16*   projT  = (u16*)alloc((size_t)CDIM * CDIM * 2);
  u16*   fc1T   = (u16*)alloc((size_t)1536 * CDIM * 2);
  u16*   fc2T   = (u16*)alloc((size_t)CDIM * 1536 * 2);
  u16*   qkvb   = (u16*)alloc((size_t)2 * NTOK * QKVD * 2);
  u16*   obf    = (u16*)alloc((size_t)2 * NTOK * CDIM * 2);
  u16*   h1bf   = (u16*)alloc((size_t)2 * NTOK * 1536 * 2);
  float* h2     = (float*)alloc((size_t)2 * NTOK * CDIM * 4);
  float* attn   = (float*)alloc((size_t)2 * NTOK * CDIM * 4);
  float* pooled = (float*)alloc((size_t)2 * CDIM * 4);
  float* gate   = (float*)alloc((size_t)2 * CDIM * 4);

  pool_hint_kernel<<<dim3(128), 256, 0, stream>>>(ah, hint);
  finalize_edge_kernel<<<dim3(2), 1024, 0, stream>>>(hint, edge, qidx, ecnt);
  ln_kernel<<<dim3(8192), 256, 0, stream>>>(x, ln_g, ln_b, lnbf, xbf);
  transpose_kernel<<<dim3(72, 24), 256, 0, stream>>>(qkv_w, qkvT, 768, 2304);
  transpose_kernel<<<dim3(24, 24), 256, 0, stream>>>(proj_w, projT, 768, 768);
  transpose_kernel<<<dim3(48, 24), 256, 0, stream>>>(fc1_w, fc1T, 768, 1536);
  transpose_kernel<<<dim3(24, 48), 256, 0, stream>>>(fc2_w, fc2T, 1536, 768);

  gemm_bt<0><<<dim3(64, 18), 256, 0, stream>>>(xbf, qkvT, qkv_b, nullptr, qkvb, 8192, 2304, 768);
  flash_kernel<<<dim3(32, 24), 256, 0, stream>>>(qkvb, qidx, obf);
  gemm_bt<1><<<dim3(64, 6), 256, 0, stream>>>(obf, projT, proj_b, x, attn, 8192, 768, 768);
  gemm_bt<2><<<dim3(64, 12), 256, 0, stream>>>(lnbf, fc1T, fc1_b, nullptr, h1bf, 8192, 1536, 768);
  gemm_bt<3><<<dim3(64, 6), 256, 0, stream>>>(h1bf, fc2T, fc2_b, nullptr, h2, 8192, 768, 1536);

  hipMemsetAsync(pooled, 0, (size_t)2 * CDIM * 4, stream);
  pool_partial_kernel<<<dim3(96), 256, 0, stream>>>(h2, edge, pooled);
  eca_kernel<<<dim3(2), 768, 0, stream>>>(pooled, eca_w, ecnt, gate);
  combine_kernel<<<dim3(6144), 256, 0, stream>>>(x, attn, h2, gate, edge, out);
}

// Round 2
// 542.345 us; speedup vs baseline: 1.0203x; 1.0203x over previous
//
#include <hip/hip_runtime.h>

using u16 = unsigned short;
using short8 = __attribute__((ext_vector_type(8))) short;
using f32x4 = __attribute__((ext_vector_type(4))) float;

#define NTOK 4096
#define CDIM 768
#define QKVD 2304
#define NHEAD 12

__device__ __forceinline__ u16 f2bf(float f) {
  unsigned u = __float_as_uint(f);
  u += 0x7FFFu + ((u >> 16) & 1u);
  return (u16)(u >> 16);
}
__device__ __forceinline__ float bf2f(u16 v) {
  return __uint_as_float(((unsigned)v) << 16);
}

__device__ __forceinline__ void gload_lds16(const void* g, void* l) {
  __builtin_amdgcn_global_load_lds(
      (__attribute__((address_space(1))) void*)g,
      (__attribute__((address_space(3))) void*)l, 16u, 0, 0u);
}

__device__ __forceinline__ float gelu_exact(float z) {
  return 0.5f * z * (1.0f + erff(z * 0.70710678118654752f));
}

// ---------------- edge mask: pool 16x16 blocks of alpha_hint ----------------
__global__ __launch_bounds__(256) void pool_hint_kernel(
    const float* __restrict__ ah, float* __restrict__ hint)
{
  const int bid = blockIdx.x;            // B*64 blocks: (b, cellrow)
  const int b = bid >> 6, cr = bid & 63;
  const int t = threadIdx.x;
  const float* base = ah + ((size_t)b * 1024 + (size_t)cr * 16) * 1024;
  float s = 0.f;
#pragma unroll
  for (int pr = 0; pr < 16; ++pr) {
    float4 v = *(const float4*)(base + (size_t)pr * 1024 + t * 4);
    s += v.x + v.y + v.z + v.w;
  }
  s += __shfl_xor(s, 1);
  s += __shfl_xor(s, 2);
  if ((t & 3) == 0)
    hint[b * NTOK + cr * 64 + (t >> 2)] = s * (1.f / 256.f);
}

__global__ __launch_bounds__(1024) void finalize_edge_kernel(
    const float* __restrict__ hint, int* __restrict__ edge,
    int* __restrict__ qidx, int* __restrict__ eidx,
    int* __restrict__ cntE, int* __restrict__ cntZ)
{
  const int b = blockIdx.x, t = threadIdx.x;
  __shared__ int wsum[16];
  __shared__ int scntE, scntZ, stot;
  int bits[4]; int s = 0;
#pragma unroll
  for (int j = 0; j < 4; ++j) {
    float h = hint[b * NTOK + t * 4 + j];
    bits[j] = (h > 0.02f && h < 0.98f) ? 1 : 0;
    s += bits[j];
    qidx[b * NTOK + t * 4 + j] = -1;
    eidx[b * NTOK + t * 4 + j] = -1;
  }
  int sw = s;
#pragma unroll
  for (int d = 1; d < 64; d <<= 1) sw += __shfl_xor(sw, d);
  const int l = t & 63, w = t >> 6;
  if (l == 0) wsum[w] = sw;
  if (t == 0) { scntE = 0; scntZ = 0; }
  __syncthreads();
  if (t == 0) { int a = 0; for (int i = 0; i < 16; ++i) a += wsum[i]; stot = a; }
  __syncthreads();
  const bool fb = stot < 64;     // fallback: route everything to attention
#pragma unroll
  for (int j = 0; j < 4; ++j) {
    int e = fb ? 1 : bits[j];
    edge[b * NTOK + t * 4 + j] = e;
    if (e) {
      int p = atomicAdd(&scntE, 1);
      qidx[b * NTOK + p] = t * 4 + j;
    } else {
      int p = atomicAdd(&scntZ, 1);
      eidx[b * NTOK + p] = t * 4 + j;
    }
  }
  __syncthreads();
  if (t == 0) { cntE[b] = scntE; cntZ[b] = scntZ; }
}

// ---------------- LayerNorm (writes ln bf16) + x->bf16 ----------------
__global__ __launch_bounds__(256) void ln_kernel(
    const float* __restrict__ x, const float* __restrict__ gam,
    const float* __restrict__ bet, u16* __restrict__ lnb, u16* __restrict__ xb)
{
  const int row = blockIdx.x, t = threadIdx.x;
  const float* xr = x + (size_t)row * CDIM;
  float v[3];
#pragma unroll
  for (int j = 0; j < 3; ++j) v[j] = xr[t + j * 256];
  float s = v[0] + v[1] + v[2];
  float ss = v[0] * v[0] + v[1] * v[1] + v[2] * v[2];
#pragma unroll
  for (int d = 1; d < 64; d <<= 1) { s += __shfl_xor(s, d); ss += __shfl_xor(ss, d); }
  __shared__ float red[8];
  const int l = t & 63, w = t >> 6;
  if (l == 0) { red[w * 2] = s; red[w * 2 + 1] = ss; }
  __syncthreads();
  s = red[0] + red[2] + red[4] + red[6];
  ss = red[1] + red[3] + red[5] + red[7];
  const float mu = s * (1.f / 768.f);
  const float rstd = rsqrtf(ss * (1.f / 768.f) - mu * mu + 1e-5f);
#pragma unroll
  for (int j = 0; j < 3; ++j) {
    const int cc = t + j * 256;
    lnb[(size_t)row * CDIM + cc] = f2bf((v[j] - mu) * rstd * gam[cc] + bet[cc]);
    xb[(size_t)row * CDIM + cc] = f2bf(v[j]);
  }
}

// ---------------- fp32 [K,N] -> bf16 [N,K] transpose ----------------
__global__ __launch_bounds__(256) void transpose_kernel(
    const float* __restrict__ in, u16* __restrict__ outp, int K, int N)
{
  __shared__ float tile[32][33];
  const int bx = blockIdx.x, by = blockIdx.y;       // (N/32, K/32)
  const int tx = threadIdx.x & 31, ty = threadIdx.x >> 5;
#pragma unroll
  for (int j = 0; j < 32; j += 8)
    tile[ty + j][tx] = in[(size_t)(by * 32 + ty + j) * N + bx * 32 + tx];
  __syncthreads();
#pragma unroll
  for (int j = 0; j < 32; j += 8)
    outp[(size_t)(bx * 32 + ty + j) * K + by * 32 + tx] = f2bf(tile[tx][ty + j]);
}

// ---------------- bf16 MFMA GEMM with optional row gather/scatter ----------------
// EPI: 0 = +bias -> bf16 (compact out); 1 = +bias+resid -> f32 (scatter out);
//      2 = gelu(gelu(+bias)) -> bf16 (compact out); 3 = +bias -> f32 (scatter out)
// Batch geometry fixed: M-space = 2 batches x 4096 positions, 32 M-blocks/batch.
template <int EPI, bool GATHER_A, bool SCATTER_OUT>
__global__ __launch_bounds__(256) void gemm_bt(
    const u16* __restrict__ A, const u16* __restrict__ Bt,
    const float* __restrict__ bias, const float* __restrict__ resid,
    const int* __restrict__ list, void* __restrict__ outp, int N, int K)
{
  const int bm = blockIdx.x, bn = blockIdx.y;
  const int b = bm >> 5, bmi = bm & 31;
  const int rb = bmi * 128;                         // position base within batch
  if (list[b * NTOK + rb] < 0) return;              // whole block beyond count

  __shared__ __align__(16) u16 lA[128 * 32];
  __shared__ __align__(16) u16 lB[128 * 32];
  const int t = threadIdx.x;
  const int l = t & 63, w = t >> 6;
  const int g = l >> 4, c = l & 15;
  const int wr = w >> 1, wc = w & 1;

  f32x4 acc[4][4];
#pragma unroll
  for (int i = 0; i < 4; ++i)
#pragma unroll
    for (int j = 0; j < 4; ++j) acc[i][j] = f32x4{0.f, 0.f, 0.f, 0.f};

  const int srow = t >> 2;                      // 0..63
  const int sslot = (t & 3) ^ (srow & 3);       // pre-swizzled source slot
  int ta0, ta1;
  if constexpr (GATHER_A) {
    ta0 = list[b * NTOK + rb + srow];       if (ta0 < 0) ta0 = 0;
    ta1 = list[b * NTOK + rb + 64 + srow];  if (ta1 < 0) ta1 = 0;
  } else {
    ta0 = rb + srow;
    ta1 = rb + 64 + srow;
  }
  const u16* gA0 = A + ((size_t)b * NTOK + ta0) * K + sslot * 8;
  const u16* gA1 = A + ((size_t)b * NTOK + ta1) * K + sslot * 8;
  const u16* gB0 = Bt + (size_t)(bn * 128 + srow) * K + sslot * 8;
  const u16* gB1 = Bt + (size_t)(bn * 128 + 64 + srow) * K + sslot * 8;
  char* ldA = (char*)lA + w * 1024;
  char* ldB = (char*)lB + w * 1024;

  for (int k0 = 0; k0 < K; k0 += 32) {
    __syncthreads();
    gload_lds16(gA0 + k0, ldA);
    gload_lds16(gA1 + k0, ldA + 4096);
    gload_lds16(gB0 + k0, ldB);
    gload_lds16(gB1 + k0, ldB + 4096);
    __syncthreads();
    short8 af[4], bfr[4];
#pragma unroll
    for (int mi = 0; mi < 4; ++mi) {
      int row = wr * 64 + mi * 16 + c;
      af[mi] = *(const short8*)((const char*)lA + row * 64 + ((g ^ (row & 3)) << 4));
    }
#pragma unroll
    for (int ni = 0; ni < 4; ++ni) {
      int row = wc * 64 + ni * 16 + c;
      bfr[ni] = *(const short8*)((const char*)lB + row * 64 + ((g ^ (row & 3)) << 4));
    }
#pragma unroll
    for (int mi = 0; mi < 4; ++mi)
#pragma unroll
      for (int ni = 0; ni < 4; ++ni)
        acc[mi][ni] = __builtin_amdgcn_mfma_f32_16x16x32_bf16(af[mi], bfr[ni], acc[mi][ni], 0, 0, 0);
  }

#pragma unroll
  for (int mi = 0; mi < 4; ++mi) {
#pragma unroll
    for (int ni = 0; ni < 4; ++ni) {
      const int col = bn * 128 + wc * 64 + ni * 16 + c;
      const float bv = bias[col];
      const int prow0 = rb + wr * 64 + mi * 16 + g * 4;
#pragma unroll
      for (int r = 0; r < 4; ++r) {
        float v = acc[mi][ni][r] + bv;
        int orow;
        if constexpr (SCATTER_OUT) {
          int tok = list[b * NTOK + prow0 + r];
          if (tok < 0) continue;
          orow = tok;
        } else {
          orow = prow0 + r;
        }
        const size_t idx = ((size_t)b * NTOK + orow) * N + col;
        if constexpr (EPI == 0) {
          ((u16*)outp)[idx] = f2bf(v);
        } else if constexpr (EPI == 1) {
          ((float*)outp)[idx] = v + resid[idx];
        } else if constexpr (EPI == 2) {
          ((u16*)outp)[idx] = f2bf(gelu_exact(gelu_exact(v)));
        } else {
          ((float*)outp)[idx] = v;
        }
      }
    }
  }
}

// ---------------- flash attention partials over compacted edge tokens ----------------
// grid (32 qblocks, 24 bh, NSPLIT); partials: unnormalized O (bf16) + (m,l)
#define NSPLIT 2
__global__ __launch_bounds__(256) void flash_part_kernel(
    const u16* __restrict__ qkv, const int* __restrict__ cntE,
    u16* __restrict__ partO, float2* __restrict__ partML)
{
  const int qt = blockIdx.x;
  const int bh = blockIdx.y;
  const int sp = blockIdx.z;
  const int b = bh / NHEAD, h = bh % NHEAD;
  const int cnt = cntE[b];
  if (qt * 128 >= cnt) return;

  const int ntiles = (cnt + 63) >> 6;
  const int half = (ntiles + NSPLIT - 1) / NSPLIT;
  const int tA = sp * half;
  const int tB = min(ntiles, tA + half);

  __shared__ __align__(16) u16 lK[64 * 64];      // [key][dim], source-swizzled
  __shared__ __align__(16) u16 lV[64 * 64];      // [dim][key], swizzled
  __shared__ __align__(16) u16 lP[4][32 * 64];   // per-wave P, swizzled

  const int t = threadIdx.x;
  const int l = t & 63, w = t >> 6;
  const int g = l >> 4, c = l & 15;
  const size_t tokbase = (size_t)b * NTOK;

  short8 qf[2][2];
#pragma unroll
  for (int mi = 0; mi < 2; ++mi) {
    const int pos = qt * 128 + w * 32 + mi * 16 + c;   // compact position (may be >= cnt: garbage, masked at store)
    const u16* qp = qkv + (tokbase + pos) * QKVD + h * 64;
#pragma unroll
    for (int kb = 0; kb < 2; ++kb)
      qf[mi][kb] = *(const short8*)(qp + kb * 32 + g * 8);
  }

  f32x4 oacc[2][4];
  float mrun[2][4], lrun[2][4];
#pragma unroll
  for (int mi = 0; mi < 2; ++mi) {
#pragma unroll
    for (int nd = 0; nd < 4; ++nd) oacc[mi][nd] = f32x4{0.f, 0.f, 0.f, 0.f};
#pragma unroll
    for (int r = 0; r < 4; ++r) { mrun[mi][r] = -1e30f; lrun[mi][r] = 0.f; }
  }

  u16* lPw = lP[w];

  for (int kt = tA; kt < tB; ++kt) {
    __syncthreads();
    // stage K: direct compact rows, swizzled global source -> linear LDS
#pragma unroll
    for (int j = 0; j < 2; ++j) {
      int seg = j * 256 + t;
      int row = seg >> 3;
      int sl = (seg & 7) ^ (row & 7);
      gload_lds16(qkv + (tokbase + kt * 64 + row) * QKVD + CDIM + h * 64 + sl * 8,
                  (char*)lK + j * 4096 + w * 1024);
    }
    // stage V transposed with swizzle, packed u32 writes (key pairs)
    {
      const int kp = t & 31, db = t >> 5;          // db 0..7 -> d range db*8..+8
      const u16* vg = qkv + (tokbase + kt * 64 + kp * 2) * QKVD + 2 * CDIM + h * 64 + db * 8;
      union { uint4 q; u16 s[8]; } v0, v1;
      v0.q = *(const uint4*)vg;
      v1.q = *(const uint4*)(vg + QKVD);
#pragma unroll
      for (int j = 0; j < 8; ++j) {
        int d = db * 8 + j;
        unsigned pk = (unsigned)v0.s[j] | ((unsigned)v1.s[j] << 16);
        *(unsigned*)((char*)lV + d * 128 + ((kp * 4) ^ ((d & 7) << 4))) = pk;
      }
    }
    __syncthreads();

    // S = Q K^T
    short8 kf[4][2];
#pragma unroll
    for (int ni = 0; ni < 4; ++ni) {
      int row = ni * 16 + c;
#pragma unroll
      for (int kb = 0; kb < 2; ++kb)
        kf[ni][kb] = *(const short8*)((const char*)lK + row * 128 + (((kb * 4 + g) ^ (row & 7)) << 4));
    }
    f32x4 s[2][4];
#pragma unroll
    for (int mi = 0; mi < 2; ++mi)
#pragma unroll
      for (int ni = 0; ni < 4; ++ni) {
        f32x4 sv = f32x4{0.f, 0.f, 0.f, 0.f};
        sv = __builtin_amdgcn_mfma_f32_16x16x32_bf16(qf[mi][0], kf[ni][0], sv, 0, 0, 0);
        sv = __builtin_amdgcn_mfma_f32_16x16x32_bf16(qf[mi][1], kf[ni][1], sv, 0, 0, 0);
        s[mi][ni] = sv;
      }

    float emask[4];
#pragma unroll
    for (int ni = 0; ni < 4; ++ni)
      emask[ni] = (kt * 64 + ni * 16 + c < cnt) ? 0.f : -1e9f;

#pragma unroll
    for (int mi = 0; mi < 2; ++mi) {
      float mx[4];
#pragma unroll
      for (int r = 0; r < 4; ++r) {
        float a0 = s[mi][0][r] * 0.125f + emask[0];
        float a1 = s[mi][1][r] * 0.125f + emask[1];
        float a2 = s[mi][2][r] * 0.125f + emask[2];
        float a3 = s[mi][3][r] * 0.125f + emask[3];
        s[mi][0][r] = a0; s[mi][1][r] = a1; s[mi][2][r] = a2; s[mi][3][r] = a3;
        mx[r] = fmaxf(fmaxf(a0, a1), fmaxf(a2, a3));
      }
#pragma unroll
      for (int r = 0; r < 4; ++r)
#pragma unroll
        for (int d = 1; d < 16; d <<= 1)
          mx[r] = fmaxf(mx[r], __shfl_xor(mx[r], d));

      float alpha[4], rs[4];
#pragma unroll
      for (int r = 0; r < 4; ++r) {
        float mnew = fmaxf(mrun[mi][r], mx[r]);
        alpha[r] = __expf(mrun[mi][r] - mnew);
        mrun[mi][r] = mnew;
        float accp = 0.f;
        const int prow = mi * 16 + g * 4 + r;
#pragma unroll
        for (int ni = 0; ni < 4; ++ni) {
          float p = __expf(s[mi][ni][r] - mnew);
          accp += p;
          *(u16*)((char*)lPw + prow * 128 + (((ni * 16 + c) * 2) ^ ((prow & 7) << 4))) = f2bf(p);
        }
        rs[r] = accp;
      }
#pragma unroll
      for (int r = 0; r < 4; ++r)
#pragma unroll
        for (int d = 1; d < 16; d <<= 1) rs[r] += __shfl_xor(rs[r], d);
#pragma unroll
      for (int r = 0; r < 4; ++r) {
        lrun[mi][r] = lrun[mi][r] * alpha[r] + rs[r];
#pragma unroll
        for (int nd = 0; nd < 4; ++nd) oacc[mi][nd][r] *= alpha[r];
      }
    }

    // O += P V
#pragma unroll
    for (int kb = 0; kb < 2; ++kb) {
      short8 pa[2], vf[4];
#pragma unroll
      for (int mi = 0; mi < 2; ++mi) {
        int prow = mi * 16 + c;
        pa[mi] = *(const short8*)((const char*)lPw + prow * 128 + (((kb * 4 + g) ^ (prow & 7)) << 4));
      }
#pragma unroll
      for (int nd = 0; nd < 4; ++nd) {
        int vrow = nd * 16 + c;
        vf[nd] = *(const short8*)((const char*)lV + vrow * 128 + (((kb * 4 + g) ^ (vrow & 7)) << 4));
      }
#pragma unroll
      for (int mi = 0; mi < 2; ++mi)
#pragma unroll
        for (int nd = 0; nd < 4; ++nd)
          oacc[mi][nd] = __builtin_amdgcn_mfma_f32_16x16x32_bf16(pa[mi], vf[nd], oacc[mi][nd], 0, 0, 0);
    }
  }

  // store partials (unnormalized O + m,l) at compact positions
  const size_t pobase = ((size_t)(sp * 2 + b) * NHEAD + h) * NTOK;
#pragma unroll
  for (int mi = 0; mi < 2; ++mi) {
#pragma unroll
    for (int r = 0; r < 4; ++r) {
      const int pos = qt * 128 + w * 32 + mi * 16 + g * 4 + r;
      if (pos < cnt) {
        u16* op = partO + (pobase + pos) * 64;
#pragma unroll
        for (int nd = 0; nd < 4; ++nd)
          op[nd * 16 + c] = f2bf(oacc[mi][nd][r]);
        if (c == 0)
          partML[pobase + pos] = make_float2(mrun[mi][r], lrun[mi][r]);
      }
    }
  }
}

// ---------------- merge split partials -> compact obf (bf16) ----------------
__global__ __launch_bounds__(256) void flash_merge_kernel(
    const u16* __restrict__ partO, const float2* __restrict__ partML,
    const int* __restrict__ cntE, u16* __restrict__ obf)
{
  const int bh = blockIdx.y;
  const int b = bh / NHEAD, h = bh % NHEAD;
  const int t = threadIdx.x;
  const int pos = blockIdx.x * 4 + (t >> 6);
  const int d = t & 63;
  if (pos >= cntE[b]) return;
  const size_t p0 = ((size_t)(0 * 2 + b) * NHEAD + h) * NTOK + pos;
  const size_t p1 = ((size_t)(1 * 2 + b) * NHEAD + h) * NTOK + pos;
  const float2 ml0 = partML[p0];
  const float2 ml1 = partML[p1];
  const float M = fmaxf(ml0.x, ml1.x);
  const float e0 = __expf(ml0.x - M);
  const float e1 = __expf(ml1.x - M);
  const float L = ml0.y * e0 + ml1.y * e1;
  const float o = (e0 * bf2f(partO[p0 * 64 + d]) + e1 * bf2f(partO[p1 * 64 + d])) / L;
  obf[((size_t)b * NTOK + pos) * CDIM + h * 64 + d] = f2bf(o);
}

// ---------------- masked mean pool partials ----------------
__global__ __launch_bounds__(256) void pool_partial_kernel(
    const float* __restrict__ h2, const int* __restrict__ edge, float* __restrict__ pooled)
{
  const int bid = blockIdx.x;                 // 96 = b*48 + cg*16 + ts
  const int b = bid / 48, rm = bid % 48;
  const int cg = rm / 16, ts = rm % 16;
  const int ch = cg * 256 + threadIdx.x;
  float s = 0.f;
  for (int tok = ts * 256; tok < ts * 256 + 256; ++tok) {
    if (!edge[b * NTOK + tok])
      s += h2[((size_t)b * NTOK + tok) * CDIM + ch];
  }
  atomicAdd(&pooled[b * CDIM + ch], s);
}

// ---------------- ECA conv(5) + sigmoid ----------------
__global__ void eca_kernel(const float* __restrict__ pooled, const float* __restrict__ w5,
                           const int* __restrict__ ecnt, float* __restrict__ gate)
{
  const int b = blockIdx.x, c = threadIdx.x;
  const float inv = 1.f / fmaxf((float)ecnt[b], 1.f);
  float a = 0.f;
#pragma unroll
  for (int j = 0; j < 5; ++j) {
    int i = c - 2 + j;
    if (i >= 0 && i < CDIM) a += w5[j] * pooled[b * CDIM + i];
  }
  a *= inv;
  gate[b * CDIM + c] = 1.f / (1.f + __expf(-a));
}

// ---------------- final scatter-combine ----------------
__global__ __launch_bounds__(256) void combine_kernel(
    const float* __restrict__ x, const float* __restrict__ attn,
    const float* __restrict__ h2, const float* __restrict__ gate,
    const int* __restrict__ edge, float* __restrict__ out)
{
  const size_t i = ((size_t)blockIdx.x * 256 + threadIdx.x) * 4;
  const int b = (int)(i / ((size_t)NTOK * CDIM));
  const size_t r = i % ((size_t)NTOK * CDIM);
  const int tok = (int)(r / CDIM);
  const int cc = (int)(r % CDIM);
  float4 ov;
  if (edge[b * NTOK + tok]) {
    ov = *(const float4*)(attn + i);
  } else {
    float4 xv = *(const float4*)(x + i);
    float4 hv = *(const float4*)(h2 + i);
    float4 gv = *(const float4*)(gate + b * CDIM + cc);
    ov.x = xv.x + hv.x * gv.x;
    ov.y = xv.y + hv.y * gv.y;
    ov.z = xv.z + hv.z * gv.z;
    ov.w = xv.w + hv.w * gv.w;
  }
  *(float4*)(out + i) = ov;
}

extern "C" void kernel_launch(void* const* d_in, const int* in_sizes, int n_in,
                              void* d_out, int out_size, void* d_ws, size_t ws_size,
                              hipStream_t stream) {
  const float* x      = (const float*)d_in[0];
  const float* ah     = (const float*)d_in[1];
  const float* qkv_w  = (const float*)d_in[2];
  const float* qkv_b  = (const float*)d_in[3];
  const float* proj_w = (const float*)d_in[4];
  const float* proj_b = (const float*)d_in[5];
  const float* ln_g   = (const float*)d_in[6];
  const float* ln_b   = (const float*)d_in[7];
  const float* fc1_w  = (const float*)d_in[8];
  const float* fc1_b  = (const float*)d_in[9];
  const float* fc2_w  = (const float*)d_in[10];
  const float* fc2_b  = (const float*)d_in[11];
  const float* eca_w  = (const float*)d_in[12];
  float* out = (float*)d_out;

  char* ws = (char*)d_ws;
  size_t off = 0;
  auto alloc = [&](size_t bytes) {
    char* p = ws + off;
    off += (bytes + 255) & ~(size_t)255;
    return p;
  };
  float* hint   = (float*)alloc((size_t)2 * NTOK * 4);
  int*   edge   = (int*)alloc((size_t)2 * NTOK * 4);
  int*   qidx   = (int*)alloc((size_t)2 * NTOK * 4);
  int*   eidx   = (int*)alloc((size_t)2 * NTOK * 4);
  int*   cntE   = (int*)alloc(256);
  int*   cntZ   = (int*)alloc(256);
  u16*   xbf    = (u16*)alloc((size_t)2 * NTOK * CDIM * 2);
  u16*   lnbf   = (u16*)alloc((size_t)2 * NTOK * CDIM * 2);
  u16*   qkvT   = (u16*)alloc((size_t)QKVD * CDIM * 2);
  u16*   projT  = (u16*)alloc((size_t)CDIM * CDIM * 2);
  u16*   fc1T   = (u16*)alloc((size_t)1536 * CDIM * 2);
  u16*   fc2T   = (u16*)alloc((size_t)CDIM * 1536 * 2);
  u16*   qkvb   = (u16*)alloc((size_t)2 * NTOK * QKVD * 2);
  u16*   obf    = (u16*)alloc((size_t)2 * NTOK * CDIM * 2);
  u16*   h1bf   = (u16*)alloc((size_t)2 * NTOK * 1536 * 2);
  float* h2     = (float*)alloc((size_t)2 * NTOK * CDIM * 4);
  float* attn   = (float*)alloc((size_t)2 * NTOK * CDIM * 4);
  u16*   partO  = (u16*)alloc((size_t)NSPLIT * 2 * NHEAD * NTOK * 64 * 2);
  float* partML = (float*)alloc((size_t)NSPLIT * 2 * NHEAD * NTOK * 8);
  float* pooled = (float*)alloc((size_t)2 * CDIM * 4);
  float* gate   = (float*)alloc((size_t)2 * CDIM * 4);

  pool_hint_kernel<<<dim3(128), 256, 0, stream>>>(ah, hint);
  finalize_edge_kernel<<<dim3(2), 1024, 0, stream>>>(hint, edge, qidx, eidx, cntE, cntZ);
  ln_kernel<<<dim3(8192), 256, 0, stream>>>(x, ln_g, ln_b, lnbf, xbf);
  transpose_kernel<<<dim3(72, 24), 256, 0, stream>>>(qkv_w, qkvT, 768, 2304);
  transpose_kernel<<<dim3(24, 24), 256, 0, stream>>>(proj_w, projT, 768, 768);
  transpose_kernel<<<dim3(48, 24), 256, 0, stream>>>(fc1_w, fc1T, 768, 1536);
  transpose_kernel<<<dim3(24, 48), 256, 0, stream>>>(fc2_w, fc2T, 1536, 768);

  // qkv: gather edge rows -> compact qkvb
  gemm_bt<0, true, false><<<dim3(64, 18), 256, 0, stream>>>(
      xbf, qkvT, qkv_b, nullptr, qidx, qkvb, 2304, 768);
  // flash over compact rows, split-K partials + merge
  flash_part_kernel<<<dim3(32, 24, NSPLIT), 256, 0, stream>>>(qkvb, cntE, partO, (float2*)partML);
  flash_merge_kernel<<<dim3(1024, 24), 256, 0, stream>>>(partO, (const float2*)partML, cntE, obf);
  // proj: direct compact A, scatter to full attn (+resid x)
  gemm_bt<1, false, true><<<dim3(64, 6), 256, 0, stream>>>(
      obf, projT, proj_b, x, qidx, attn, 768, 768);
  // fc1: gather easy rows -> compact h1
  gemm_bt<2, true, false><<<dim3(64, 12), 256, 0, stream>>>(
      lnbf, fc1T, fc1_b, nullptr, eidx, h1bf, 1536, 768);
  // fc2: direct compact A, scatter to full h2
  gemm_bt<3, false, true><<<dim3(64, 6), 256, 0, stream>>>(
      h1bf, fc2T, fc2_b, nullptr, eidx, h2, 768, 1536);

  hipMemsetAsync(pooled, 0, (size_t)2 * CDIM * 4, stream);
  pool_partial_kernel<<<dim3(96), 256, 0, stream>>>(h2, edge, pooled);
  eca_kernel<<<dim3(2), 768, 0, stream>>>(pooled, eca_w, cntZ, gate);
  combine_kernel<<<dim3(6144), 256, 0, stream>>>(x, attn, h2, gate, edge, out);
}

// Round 4
// 530.846 us; speedup vs baseline: 1.0424x; 1.0217x over previous
//
#include <hip/hip_runtime.h>

using u16 = unsigned short;
using short8 = __attribute__((ext_vector_type(8))) short;
using f32x4 = __attribute__((ext_vector_type(4))) float;

#define NTOK 4096
#define CDIM 768
#define QKVD 2304
#define NHEAD 12
#define NSPLIT 2
// 0.125 (1/sqrt(64)) * log2(e)
#define SCALE2 0.18033688011112042f

__device__ __forceinline__ u16 f2bf(float f) {
  unsigned u = __float_as_uint(f);
  u += 0x7FFFu + ((u >> 16) & 1u);
  return (u16)(u >> 16);
}
__device__ __forceinline__ float bf2f(u16 v) {
  return __uint_as_float(((unsigned)v) << 16);
}
__device__ __forceinline__ unsigned pkbf(float a, float b) {
  return (unsigned)f2bf(a) | ((unsigned)f2bf(b) << 16);
}

__device__ __forceinline__ void gload_lds16(const void* g, void* l) {
  __builtin_amdgcn_global_load_lds(
      (__attribute__((address_space(1))) void*)g,
      (__attribute__((address_space(3))) void*)l, 16u, 0, 0u);
}

__device__ __forceinline__ float gelu_exact(float z) {
  return 0.5f * z * (1.0f + erff(z * 0.70710678118654752f));
}

// ---------------- edge mask: pool 16x16 blocks of alpha_hint ----------------
__global__ __launch_bounds__(256) void pool_hint_kernel(
    const float* __restrict__ ah, float* __restrict__ hint)
{
  const int bid = blockIdx.x;            // B*64 blocks: (b, cellrow)
  const int b = bid >> 6, cr = bid & 63;
  const int t = threadIdx.x;
  const float* base = ah + ((size_t)b * 1024 + (size_t)cr * 16) * 1024;
  float s = 0.f;
#pragma unroll
  for (int pr = 0; pr < 16; ++pr) {
    float4 v = *(const float4*)(base + (size_t)pr * 1024 + t * 4);
    s += v.x + v.y + v.z + v.w;
  }
  s += __shfl_xor(s, 1);
  s += __shfl_xor(s, 2);
  if ((t & 3) == 0)
    hint[b * NTOK + cr * 64 + (t >> 2)] = s * (1.f / 256.f);
}

__global__ __launch_bounds__(1024) void finalize_edge_kernel(
    const float* __restrict__ hint, int* __restrict__ edge,
    int* __restrict__ qidx, int* __restrict__ eidx,
    int* __restrict__ cntE, int* __restrict__ cntZ)
{
  const int b = blockIdx.x, t = threadIdx.x;
  __shared__ int wsum[16];
  __shared__ int scntE, scntZ, stot;
  int bits[4]; int s = 0;
#pragma unroll
  for (int j = 0; j < 4; ++j) {
    float h = hint[b * NTOK + t * 4 + j];
    bits[j] = (h > 0.02f && h < 0.98f) ? 1 : 0;
    s += bits[j];
    qidx[b * NTOK + t * 4 + j] = -1;
    eidx[b * NTOK + t * 4 + j] = -1;
  }
  int sw = s;
#pragma unroll
  for (int d = 1; d < 64; d <<= 1) sw += __shfl_xor(sw, d);
  const int l = t & 63, w = t >> 6;
  if (l == 0) wsum[w] = sw;
  if (t == 0) { scntE = 0; scntZ = 0; }
  __syncthreads();
  if (t == 0) { int a = 0; for (int i = 0; i < 16; ++i) a += wsum[i]; stot = a; }
  __syncthreads();
  const bool fb = stot < 64;     // fallback: route everything to attention
#pragma unroll
  for (int j = 0; j < 4; ++j) {
    int e = fb ? 1 : bits[j];
    edge[b * NTOK + t * 4 + j] = e;
    if (e) {
      int p = atomicAdd(&scntE, 1);
      qidx[b * NTOK + p] = t * 4 + j;
    } else {
      int p = atomicAdd(&scntZ, 1);
      eidx[b * NTOK + p] = t * 4 + j;
    }
  }
  __syncthreads();
  if (t == 0) { cntE[b] = scntE; cntZ[b] = scntZ; }
}

// ---------------- LayerNorm (writes ln bf16) + x->bf16 ----------------
__global__ __launch_bounds__(256) void ln_kernel(
    const float* __restrict__ x, const float* __restrict__ gam,
    const float* __restrict__ bet, u16* __restrict__ lnb, u16* __restrict__ xb)
{
  const int row = blockIdx.x, t = threadIdx.x;
  const float* xr = x + (size_t)row * CDIM;
  float v[3];
#pragma unroll
  for (int j = 0; j < 3; ++j) v[j] = xr[t + j * 256];
  float s = v[0] + v[1] + v[2];
  float ss = v[0] * v[0] + v[1] * v[1] + v[2] * v[2];
#pragma unroll
  for (int d = 1; d < 64; d <<= 1) { s += __shfl_xor(s, d); ss += __shfl_xor(ss, d); }
  __shared__ float red[8];
  const int l = t & 63, w = t >> 6;
  if (l == 0) { red[w * 2] = s; red[w * 2 + 1] = ss; }
  __syncthreads();
  s = red[0] + red[2] + red[4] + red[6];
  ss = red[1] + red[3] + red[5] + red[7];
  const float mu = s * (1.f / 768.f);
  const float rstd = rsqrtf(ss * (1.f / 768.f) - mu * mu + 1e-5f);
#pragma unroll
  for (int j = 0; j < 3; ++j) {
    const int cc = t + j * 256;
    lnb[(size_t)row * CDIM + cc] = f2bf((v[j] - mu) * rstd * gam[cc] + bet[cc]);
    xb[(size_t)row * CDIM + cc] = f2bf(v[j]);
  }
}

// ---------------- fused fp32 [K,N] -> bf16 [N,K] transposes (4 weights) ----------------
__global__ __launch_bounds__(256) void transpose_all_kernel(
    const float* __restrict__ qkv_w, const float* __restrict__ proj_w,
    const float* __restrict__ fc1_w, const float* __restrict__ fc2_w,
    u16* __restrict__ qkvT, u16* __restrict__ projT,
    u16* __restrict__ fc1T, u16* __restrict__ fc2T)
{
  __shared__ float tile[32][33];
  int bid = blockIdx.x;
  const float* in; u16* outp; int K, N, bx, by;
  if (bid < 1728)      { in = qkv_w;  outp = qkvT; K = 768;  N = 2304; bx = bid % 72; by = bid / 72; }
  else if (bid < 2304) { bid -= 1728; in = proj_w; outp = projT; K = 768;  N = 768;  bx = bid % 24; by = bid / 24; }
  else if (bid < 3456) { bid -= 2304; in = fc1_w;  outp = fc1T; K = 768;  N = 1536; bx = bid % 48; by = bid / 48; }
  else                 { bid -= 3456; in = fc2_w;  outp = fc2T; K = 1536; N = 768;  bx = bid % 24; by = bid / 24; }
  const int tx = threadIdx.x & 31, ty = threadIdx.x >> 5;
#pragma unroll
  for (int j = 0; j < 32; j += 8)
    tile[ty + j][tx] = in[(size_t)(by * 32 + ty + j) * N + bx * 32 + tx];
  __syncthreads();
#pragma unroll
  for (int j = 0; j < 32; j += 8)
    outp[(size_t)(bx * 32 + ty + j) * K + by * 32 + tx] = f2bf(tile[tx][ty + j]);
}

// ---------------- bf16 MFMA GEMM with optional row gather/scatter ----------------
// EPI: 0 = +bias -> bf16 (compact out); 1 = +bias+resid -> f32 (scatter out);
//      2 = gelu(gelu(+bias)) -> bf16 (compact out); 3 = +bias -> f32 (scatter out)
template <int EPI, bool GATHER_A, bool SCATTER_OUT>
__global__ __launch_bounds__(256) void gemm_bt(
    const u16* __restrict__ A, const u16* __restrict__ Bt,
    const float* __restrict__ bias, const float* __restrict__ resid,
    const int* __restrict__ list, void* __restrict__ outp, int N, int K)
{
  const int bm = blockIdx.x, bn = blockIdx.y;
  const int b = bm >> 5, bmi = bm & 31;
  const int rb = bmi * 128;                         // position base within batch
  if (list[b * NTOK + rb] < 0) return;              // whole block beyond count

  __shared__ __align__(16) u16 lA[128 * 32];
  __shared__ __align__(16) u16 lB[128 * 32];
  const int t = threadIdx.x;
  const int l = t & 63, w = t >> 6;
  const int g = l >> 4, c = l & 15;
  const int wr = w >> 1, wc = w & 1;

  f32x4 acc[4][4];
#pragma unroll
  for (int i = 0; i < 4; ++i)
#pragma unroll
    for (int j = 0; j < 4; ++j) acc[i][j] = f32x4{0.f, 0.f, 0.f, 0.f};

  const int srow = t >> 2;                      // 0..63
  const int sslot = (t & 3) ^ (srow & 3);       // pre-swizzled source slot
  int ta0, ta1;
  if constexpr (GATHER_A) {
    ta0 = list[b * NTOK + rb + srow];       if (ta0 < 0) ta0 = 0;
    ta1 = list[b * NTOK + rb + 64 + srow];  if (ta1 < 0) ta1 = 0;
  } else {
    ta0 = rb + srow;
    ta1 = rb + 64 + srow;
  }
  const u16* gA0 = A + ((size_t)b * NTOK + ta0) * K + sslot * 8;
  const u16* gA1 = A + ((size_t)b * NTOK + ta1) * K + sslot * 8;
  const u16* gB0 = Bt + (size_t)(bn * 128 + srow) * K + sslot * 8;
  const u16* gB1 = Bt + (size_t)(bn * 128 + 64 + srow) * K + sslot * 8;
  char* ldA = (char*)lA + w * 1024;
  char* ldB = (char*)lB + w * 1024;

  for (int k0 = 0; k0 < K; k0 += 32) {
    __syncthreads();
    gload_lds16(gA0 + k0, ldA);
    gload_lds16(gA1 + k0, ldA + 4096);
    gload_lds16(gB0 + k0, ldB);
    gload_lds16(gB1 + k0, ldB + 4096);
    __syncthreads();
    short8 af[4], bfr[4];
#pragma unroll
    for (int mi = 0; mi < 4; ++mi) {
      int row = wr * 64 + mi * 16 + c;
      af[mi] = *(const short8*)((const char*)lA + row * 64 + ((g ^ (row & 3)) << 4));
    }
#pragma unroll
    for (int ni = 0; ni < 4; ++ni) {
      int row = wc * 64 + ni * 16 + c;
      bfr[ni] = *(const short8*)((const char*)lB + row * 64 + ((g ^ (row & 3)) << 4));
    }
#pragma unroll
    for (int mi = 0; mi < 4; ++mi)
#pragma unroll
      for (int ni = 0; ni < 4; ++ni)
        acc[mi][ni] = __builtin_amdgcn_mfma_f32_16x16x32_bf16(af[mi], bfr[ni], acc[mi][ni], 0, 0, 0);
  }

#pragma unroll
  for (int mi = 0; mi < 4; ++mi) {
#pragma unroll
    for (int ni = 0; ni < 4; ++ni) {
      const int col = bn * 128 + wc * 64 + ni * 16 + c;
      const float bv = bias[col];
      const int prow0 = rb + wr * 64 + mi * 16 + g * 4;
#pragma unroll
      for (int r = 0; r < 4; ++r) {
        float v = acc[mi][ni][r] + bv;
        int orow;
        if constexpr (SCATTER_OUT) {
          int tok = list[b * NTOK + prow0 + r];
          if (tok < 0) continue;
          orow = tok;
        } else {
          orow = prow0 + r;
        }
        const size_t idx = ((size_t)b * NTOK + orow) * N + col;
        if constexpr (EPI == 0) {
          ((u16*)outp)[idx] = f2bf(v);
        } else if constexpr (EPI == 1) {
          ((float*)outp)[idx] = v + resid[idx];
        } else if constexpr (EPI == 2) {
          ((u16*)outp)[idx] = f2bf(gelu_exact(gelu_exact(v)));
        } else {
          ((float*)outp)[idx] = v;
        }
      }
    }
  }
}

// ---------------- flash attention partials: swapped S^T + double-buffered K/V ----------------
// grid (32 qblocks, 24 bh, NSPLIT); partials: unnormalized O (bf16) + (m2,l) base-2
__global__ __launch_bounds__(256) void flash_part_kernel(
    const u16* __restrict__ qkv, const int* __restrict__ cntE,
    u16* __restrict__ partO, float2* __restrict__ partML)
{
  const int qt = blockIdx.x;
  const int bh = blockIdx.y;
  const int sp = blockIdx.z;
  const int b = bh / NHEAD, h = bh % NHEAD;
  const int cnt = cntE[b];
  if (qt * 128 >= cnt) return;

  const int ntiles = (cnt + 63) >> 6;
  const int per = (ntiles + NSPLIT - 1) / NSPLIT;
  const int tA = sp * per;
  const int tB = min(ntiles, tA + per);
  if (tA >= tB) return;

  __shared__ __align__(16) u16 lK[2][64 * 64];   // [key][dim], source-swizzled
  __shared__ __align__(16) u16 lV[2][64 * 64];   // [dim][key], swizzled
  __shared__ __align__(16) u16 lP[4][32 * 64];   // per-wave P^T bounce [q][key], swizzled

  const int t = threadIdx.x;
  const int l = t & 63, w = t >> 6;
  const int g = l >> 4, c = l & 15;
  const int kp = t & 31, db = t >> 5;            // V staging: key-pair, d-block
  const size_t tokbase = (size_t)b * NTOK;

  // Q fragments (B-operand): lane holds q = block q-base + mi*16 + c, d-slice kb*32+g*8
  short8 qf[2][2];
#pragma unroll
  for (int mi = 0; mi < 2; ++mi) {
    const int pos = qt * 128 + w * 32 + mi * 16 + c;
    const u16* qp = qkv + (tokbase + pos) * QKVD + h * 64;
#pragma unroll
    for (int kb = 0; kb < 2; ++kb)
      qf[mi][kb] = *(const short8*)(qp + kb * 32 + g * 8);
  }

  f32x4 oacc[2][4];            // O^T: [mi(q)][nd(d)]: lane (g,c): d=nd*16+g*4+r, q=mi*16+c
  float m2run[2], lrun[2];
#pragma unroll
  for (int mi = 0; mi < 2; ++mi) {
#pragma unroll
    for (int nd = 0; nd < 4; ++nd) oacc[mi][nd] = f32x4{0.f, 0.f, 0.f, 0.f};
    m2run[mi] = -1e30f; lrun[mi] = 0.f;
  }

  char* lPw = (char*)lP[w];

  auto stageK = [&](int kt, int buf) {
#pragma unroll
    for (int j = 0; j < 2; ++j) {
      int seg = j * 256 + t;
      int row = seg >> 3;
      int sl = (seg & 7) ^ (row & 7);
      gload_lds16(qkv + (tokbase + kt * 64 + row) * QKVD + CDIM + h * 64 + sl * 8,
                  (char*)lK[buf] + j * 4096 + w * 1024);
    }
  };
  uint4 va, vb;
  auto loadV = [&](int kt) {
    const u16* vg = qkv + (tokbase + kt * 64 + kp * 2) * QKVD + 2 * CDIM + h * 64 + db * 8;
    va = *(const uint4*)vg;
    vb = *(const uint4*)(vg + QKVD);
  };
  auto writeV = [&](int buf) {
    union { uint4 q; u16 s[8]; } u0, u1; u0.q = va; u1.q = vb;
    char* lvb = (char*)lV[buf];
#pragma unroll
    for (int j = 0; j < 8; ++j) {
      int d = db * 8 + j;
      unsigned pk = (unsigned)u0.s[j] | ((unsigned)u1.s[j] << 16);
      *(unsigned*)(lvb + d * 128 + ((kp * 4) ^ ((d & 7) << 4))) = pk;
    }
  };

  int cur = 0;
  stageK(tA, 0);
  loadV(tA);
  writeV(0);
  __syncthreads();

  for (int kt = tA; kt < tB; ++kt) {
    const bool hasNext = (kt + 1 < tB);
    if (hasNext) { stageK(kt + 1, cur ^ 1); loadV(kt + 1); }

    // ---- S^T = K Q^T ----
    const char* lKc = (const char*)lK[cur];
    short8 kf[4][2];
#pragma unroll
    for (int ni = 0; ni < 4; ++ni) {
      int row = ni * 16 + c;
#pragma unroll
      for (int kb = 0; kb < 2; ++kb)
        kf[ni][kb] = *(const short8*)(lKc + row * 128 + (((kb * 4 + g) ^ (row & 7)) << 4));
    }
    f32x4 st[2][4];
    __builtin_amdgcn_s_setprio(1);
#pragma unroll
    for (int mi = 0; mi < 2; ++mi)
#pragma unroll
      for (int ni = 0; ni < 4; ++ni) {
        f32x4 sv = f32x4{0.f, 0.f, 0.f, 0.f};
        sv = __builtin_amdgcn_mfma_f32_16x16x32_bf16(kf[ni][0], qf[mi][0], sv, 0, 0, 0);
        sv = __builtin_amdgcn_mfma_f32_16x16x32_bf16(kf[ni][1], qf[mi][1], sv, 0, 0, 0);
        st[mi][ni] = sv;
      }
    __builtin_amdgcn_s_setprio(0);

    // ---- scale to base-2 + in-lane key mask ----
    const int kvalid = cnt - kt * 64;      // keys valid in this tile
#pragma unroll
    for (int mi = 0; mi < 2; ++mi)
#pragma unroll
      for (int ni = 0; ni < 4; ++ni)
#pragma unroll
        for (int r = 0; r < 4; ++r) {
          float v = st[mi][ni][r] * SCALE2;
          st[mi][ni][r] = (ni * 16 + g * 4 + r < kvalid) ? v : -1e30f;
        }

    // ---- online softmax (q per-lane; keys: 16 in-lane + 2 shfl) ----
#pragma unroll
    for (int mi = 0; mi < 2; ++mi) {
      float mx = fmaxf(
          fmaxf(fmaxf(fmaxf(st[mi][0][0], st[mi][0][1]), fmaxf(st[mi][0][2], st[mi][0][3])),
                fmaxf(fmaxf(st[mi][1][0], st[mi][1][1]), fmaxf(st[mi][1][2], st[mi][1][3]))),
          fmaxf(fmaxf(fmaxf(st[mi][2][0], st[mi][2][1]), fmaxf(st[mi][2][2], st[mi][2][3])),
                fmaxf(fmaxf(st[mi][3][0], st[mi][3][1]), fmaxf(st[mi][3][2], st[mi][3][3]))));
      mx = fmaxf(mx, __shfl_xor(mx, 16));
      mx = fmaxf(mx, __shfl_xor(mx, 32));
      const float m2new = fmaxf(m2run[mi], mx);
      const float alpha = exp2f(m2run[mi] - m2new);
      m2run[mi] = m2new;
      float rs = 0.f;
      const int qrow = mi * 16 + c;
      char* base = lPw + qrow * 128;
      const int swz = (qrow & 7) << 4;
#pragma unroll
      for (int ni = 0; ni < 4; ++ni) {
        float p0 = exp2f(st[mi][ni][0] - m2new);
        float p1 = exp2f(st[mi][ni][1] - m2new);
        float p2 = exp2f(st[mi][ni][2] - m2new);
        float p3 = exp2f(st[mi][ni][3] - m2new);
        rs += (p0 + p1) + (p2 + p3);
        *(uint2*)(base + ((ni * 32 + g * 8) ^ swz)) = make_uint2(pkbf(p0, p1), pkbf(p2, p3));
      }
      rs += __shfl_xor(rs, 16);
      rs += __shfl_xor(rs, 32);
      lrun[mi] = lrun[mi] * alpha + rs;
#pragma unroll
      for (int nd = 0; nd < 4; ++nd)
#pragma unroll
        for (int r = 0; r < 4; ++r) oacc[mi][nd][r] *= alpha;
    }

    // ---- O^T += V^T P^T ----
    const char* lVc = (const char*)lV[cur];
#pragma unroll
    for (int kb = 0; kb < 2; ++kb) {
      short8 pb[2], vf[4];
#pragma unroll
      for (int mi = 0; mi < 2; ++mi) {
        int qrow = mi * 16 + c;
        pb[mi] = *(const short8*)(lPw + qrow * 128 + (((kb * 64 + g * 16)) ^ ((qrow & 7) << 4)));
      }
#pragma unroll
      for (int nd = 0; nd < 4; ++nd) {
        int d = nd * 16 + c;
        vf[nd] = *(const short8*)(lVc + d * 128 + (((kb * 4 + g) ^ (d & 7)) << 4));
      }
      __builtin_amdgcn_s_setprio(1);
#pragma unroll
      for (int mi = 0; mi < 2; ++mi)
#pragma unroll
        for (int nd = 0; nd < 4; ++nd)
          oacc[mi][nd] = __builtin_amdgcn_mfma_f32_16x16x32_bf16(vf[nd], pb[mi], oacc[mi][nd], 0, 0, 0);
      __builtin_amdgcn_s_setprio(0);
    }

    if (hasNext) writeV(cur ^ 1);
    __syncthreads();
    cur ^= 1;
  }

  // ---- store partials: O^T lane (g,c): q=mi*16+c, d=nd*16+g*4+r ----
  const size_t pobase = ((size_t)(sp * 2 + b) * NHEAD + h) * NTOK;
#pragma unroll
  for (int mi = 0; mi < 2; ++mi) {
    const int pos = qt * 128 + w * 32 + mi * 16 + c;
    if (pos < cnt) {
      u16* op = partO + (pobase + pos) * 64;
#pragma unroll
      for (int nd = 0; nd < 4; ++nd) {
        ushort4 pk4;
        pk4.x = f2bf(oacc[mi][nd][0]);
        pk4.y = f2bf(oacc[mi][nd][1]);
        pk4.z = f2bf(oacc[mi][nd][2]);
        pk4.w = f2bf(oacc[mi][nd][3]);
        *(ushort4*)(op + nd * 16 + g * 4) = pk4;
      }
      if (g == 0)
        partML[pobase + pos] = make_float2(m2run[mi], lrun[mi]);
    }
  }
}

// ---------------- merge split partials -> compact obf (bf16) ----------------
__global__ __launch_bounds__(256) void flash_merge_kernel(
    const u16* __restrict__ partO, const float2* __restrict__ partML,
    const int* __restrict__ cntE, u16* __restrict__ obf)
{
  const int bh = blockIdx.y;
  const int b = bh / NHEAD, h = bh % NHEAD;
  const int t = threadIdx.x;
  const int pos = blockIdx.x * 4 + (t >> 6);
  const int d = t & 63;
  const int cnt = cntE[b];
  if (pos >= cnt) return;
  const int ntiles = (cnt + 63) >> 6;
  const int per = (ntiles + NSPLIT - 1) / NSPLIT;

  float2 ml[NSPLIT];
  float M = -3e38f;
  int nact = 0;
#pragma unroll
  for (int sp = 0; sp < NSPLIT; ++sp) {
    if (sp * per < ntiles) {
      ml[sp] = partML[((size_t)(sp * 2 + b) * NHEAD + h) * NTOK + pos];
      M = fmaxf(M, ml[sp].x);
      nact = sp + 1;
    }
  }
  float L = 0.f, O = 0.f;
#pragma unroll
  for (int sp = 0; sp < NSPLIT; ++sp) {
    if (sp < nact) {
      const float e = exp2f(ml[sp].x - M);
      L += ml[sp].y * e;
      O += e * bf2f(partO[(((size_t)(sp * 2 + b) * NHEAD + h) * NTOK + pos) * 64 + d]);
    }
  }
  obf[((size_t)b * NTOK + pos) * CDIM + h * 64 + d] = f2bf(O / L);
}

// ---------------- masked mean pool partials ----------------
__global__ __launch_bounds__(256) void pool_partial_kernel(
    const float* __restrict__ h2, const int* __restrict__ edge, float* __restrict__ pooled)
{
  const int bid = blockIdx.x;                 // 96 = b*48 + cg*16 + ts
  const int b = bid / 48, rm = bid % 48;
  const int cg = rm / 16, ts = rm % 16;
  const int ch = cg * 256 + threadIdx.x;
  float s = 0.f;
  for (int tok = ts * 256; tok < ts * 256 + 256; ++tok) {
    if (!edge[b * NTOK + tok])
      s += h2[((size_t)b * NTOK + tok) * CDIM + ch];
  }
  atomicAdd(&pooled[b * CDIM + ch], s);
}

// ---------------- ECA conv(5) + sigmoid ----------------
__global__ void eca_kernel(const float* __restrict__ pooled, const float* __restrict__ w5,
                           const int* __restrict__ ecnt, float* __restrict__ gate)
{
  const int b = blockIdx.x, c = threadIdx.x;
  const float inv = 1.f / fmaxf((float)ecnt[b], 1.f);
  float a = 0.f;
#pragma unroll
  for (int j = 0; j < 5; ++j) {
    int i = c - 2 + j;
    if (i >= 0 && i < CDIM) a += w5[j] * pooled[b * CDIM + i];
  }
  a *= inv;
  gate[b * CDIM + c] = 1.f / (1.f + __expf(-a));
}

// ---------------- final scatter-combine ----------------
__global__ __launch_bounds__(256) void combine_kernel(
    const float* __restrict__ x, const float* __restrict__ attn,
    const float* __restrict__ h2, const float* __restrict__ gate,
    const int* __restrict__ edge, float* __restrict__ out)
{
  const size_t i = ((size_t)blockIdx.x * 256 + threadIdx.x) * 4;
  const int b = (int)(i / ((size_t)NTOK * CDIM));
  const size_t r = i % ((size_t)NTOK * CDIM);
  const int tok = (int)(r / CDIM);
  const int cc = (int)(r % CDIM);
  float4 ov;
  if (edge[b * NTOK + tok]) {
    ov = *(const float4*)(attn + i);
  } else {
    float4 xv = *(const float4*)(x + i);
    float4 hv = *(const float4*)(h2 + i);
    float4 gv = *(const float4*)(gate + b * CDIM + cc);
    ov.x = xv.x + hv.x * gv.x;
    ov.y = xv.y + hv.y * gv.y;
    ov.z = xv.z + hv.z * gv.z;
    ov.w = xv.w + hv.w * gv.w;
  }
  *(float4*)(out + i) = ov;
}

extern "C" void kernel_launch(void* const* d_in, const int* in_sizes, int n_in,
                              void* d_out, int out_size, void* d_ws, size_t ws_size,
                              hipStream_t stream) {
  const float* x      = (const float*)d_in[0];
  const float* ah     = (const float*)d_in[1];
  const float* qkv_w  = (const float*)d_in[2];
  const float* qkv_b  = (const float*)d_in[3];
  const float* proj_w = (const float*)d_in[4];
  const float* proj_b = (const float*)d_in[5];
  const float* ln_g   = (const float*)d_in[6];
  const float* ln_b   = (const float*)d_in[7];
  const float* fc1_w  = (const float*)d_in[8];
  const float* fc1_b  = (const float*)d_in[9];
  const float* fc2_w  = (const float*)d_in[10];
  const float* fc2_b  = (const float*)d_in[11];
  const float* eca_w  = (const float*)d_in[12];
  float* out = (float*)d_out;

  char* ws = (char*)d_ws;
  size_t off = 0;
  auto alloc = [&](size_t bytes) {
    char* p = ws + off;
    off += (bytes + 255) & ~(size_t)255;
    return p;
  };
  float* hint   = (float*)alloc((size_t)2 * NTOK * 4);
  int*   edge   = (int*)alloc((size_t)2 * NTOK * 4);
  int*   qidx   = (int*)alloc((size_t)2 * NTOK * 4);
  int*   eidx   = (int*)alloc((size_t)2 * NTOK * 4);
  int*   cntE   = (int*)alloc(256);
  int*   cntZ   = (int*)alloc(256);
  u16*   xbf    = (u16*)alloc((size_t)2 * NTOK * CDIM * 2);
  u16*   lnbf   = (u16*)alloc((size_t)2 * NTOK * CDIM * 2);
  u16*   qkvT   = (u16*)alloc((size_t)QKVD * CDIM * 2);
  u16*   projT  = (u16*)alloc((size_t)CDIM * CDIM * 2);
  u16*   fc1T   = (u16*)alloc((size_t)1536 * CDIM * 2);
  u16*   fc2T   = (u16*)alloc((size_t)CDIM * 1536 * 2);
  u16*   qkvb   = (u16*)alloc((size_t)2 * NTOK * QKVD * 2);
  u16*   obf    = (u16*)alloc((size_t)2 * NTOK * CDIM * 2);
  u16*   h1bf   = (u16*)alloc((size_t)2 * NTOK * 1536 * 2);
  float* h2     = (float*)alloc((size_t)2 * NTOK * CDIM * 4);
  float* attn   = (float*)alloc((size_t)2 * NTOK * CDIM * 4);
  u16*   partO  = (u16*)alloc((size_t)NSPLIT * 2 * NHEAD * NTOK * 64 * 2);
  float* partML = (float*)alloc((size_t)NSPLIT * 2 * NHEAD * NTOK * 8);
  float* pooled = (float*)alloc((size_t)2 * CDIM * 4);
  float* gate   = (float*)alloc((size_t)2 * CDIM * 4);

  pool_hint_kernel<<<dim3(128), 256, 0, stream>>>(ah, hint);
  finalize_edge_kernel<<<dim3(2), 1024, 0, stream>>>(hint, edge, qidx, eidx, cntE, cntZ);
  ln_kernel<<<dim3(8192), 256, 0, stream>>>(x, ln_g, ln_b, lnbf, xbf);
  transpose_all_kernel<<<dim3(4608), 256, 0, stream>>>(
      qkv_w, proj_w, fc1_w, fc2_w, qkvT, projT, fc1T, fc2T);

  // qkv: gather edge rows -> compact qkvb
  gemm_bt<0, true, false><<<dim3(64, 18), 256, 0, stream>>>(
      xbf, qkvT, qkv_b, nullptr, qidx, qkvb, 2304, 768);
  // flash over compact rows, split-K partials + merge
  flash_part_kernel<<<dim3(32, 24, NSPLIT), 256, 0, stream>>>(qkvb, cntE, partO, (float2*)partML);
  flash_merge_kernel<<<dim3(1024, 24), 256, 0, stream>>>(partO, (const float2*)partML, cntE, obf);
  // proj: direct compact A, scatter to full attn (+resid x)
  gemm_bt<1, false, true><<<dim3(64, 6), 256, 0, stream>>>(
      obf, projT, proj_b, x, qidx, attn, 768, 768);
  // fc1: gather easy rows -> compact h1
  gemm_bt<2, true, false><<<dim3(64, 12), 256, 0, stream>>>(
      lnbf, fc1T, fc1_b, nullptr, eidx, h1bf, 1536, 768);
  // fc2: direct compact A, scatter to full h2
  gemm_bt<3, false, true><<<dim3(64, 6), 256, 0, stream>>>(
      h1bf, fc2T, fc2_b, nullptr, eidx, h2, 768, 1536);

  hipMemsetAsync(pooled, 0, (size_t)2 * CDIM * 4, stream);
  pool_partial_kernel<<<dim3(96), 256, 0, stream>>>(h2, edge, pooled);
  eca_kernel<<<dim3(2), 768, 0, stream>>>(pooled, eca_w, cntZ, gate);
  combine_kernel<<<dim3(6144), 256, 0, stream>>>(x, attn, h2, gate, edge, out);
}

// Round 5
// 504.461 us; speedup vs baseline: 1.0969x; 1.0523x over previous
//
#include <hip/hip_runtime.h>

using u16 = unsigned short;
using short8 = __attribute__((ext_vector_type(8))) short;
using f32x4 = __attribute__((ext_vector_type(4))) float;

#define NTOK 4096
#define CDIM 768
#define QKVD 2304
#define NHEAD 12
#define NSPLIT 4
// 0.125 (1/sqrt(64)) * log2(e)
#define SCALE2 0.18033688011112042f
// defer-max threshold: 8 (base-2) in raw-score units = 8/SCALE2
#define THRRAW 44.3614195558f

__device__ __forceinline__ u16 f2bf(float f) {
  unsigned u = __float_as_uint(f);
  u += 0x7FFFu + ((u >> 16) & 1u);
  return (u16)(u >> 16);
}
__device__ __forceinline__ float bf2f(u16 v) {
  return __uint_as_float(((unsigned)v) << 16);
}
__device__ __forceinline__ float fast_exp2(float x) {
  float r;
  asm("v_exp_f32 %0, %1" : "=v"(r) : "v"(x));
  return r;
}
__device__ __forceinline__ unsigned cvtpk(float lo, float hi) {
  unsigned r;
  asm("v_cvt_pk_bf16_f32 %0, %1, %2" : "=v"(r) : "v"(lo), "v"(hi));
  return r;
}

__device__ __forceinline__ void gload_lds16(const void* g, void* l) {
  __builtin_amdgcn_global_load_lds(
      (__attribute__((address_space(1))) void*)g,
      (__attribute__((address_space(3))) void*)l, 16u, 0, 0u);
}

__device__ __forceinline__ float gelu_exact(float z) {
  return 0.5f * z * (1.0f + erff(z * 0.70710678118654752f));
}

// ---------------- edge mask: pool 16x16 blocks of alpha_hint ----------------
__global__ __launch_bounds__(256) void pool_hint_kernel(
    const float* __restrict__ ah, float* __restrict__ hint)
{
  const int bid = blockIdx.x;            // B*64 blocks: (b, cellrow)
  const int b = bid >> 6, cr = bid & 63;
  const int t = threadIdx.x;
  const float* base = ah + ((size_t)b * 1024 + (size_t)cr * 16) * 1024;
  float s = 0.f;
#pragma unroll
  for (int pr = 0; pr < 16; ++pr) {
    float4 v = *(const float4*)(base + (size_t)pr * 1024 + t * 4);
    s += v.x + v.y + v.z + v.w;
  }
  s += __shfl_xor(s, 1);
  s += __shfl_xor(s, 2);
  if ((t & 3) == 0)
    hint[b * NTOK + cr * 64 + (t >> 2)] = s * (1.f / 256.f);
}

__global__ __launch_bounds__(1024) void finalize_edge_kernel(
    const float* __restrict__ hint, int* __restrict__ edge,
    int* __restrict__ qidx, int* __restrict__ eidx,
    int* __restrict__ cntE, int* __restrict__ cntZ)
{
  const int b = blockIdx.x, t = threadIdx.x;
  __shared__ int wsum[16];
  __shared__ int scntE, scntZ, stot;
  int bits[4]; int s = 0;
#pragma unroll
  for (int j = 0; j < 4; ++j) {
    float h = hint[b * NTOK + t * 4 + j];
    bits[j] = (h > 0.02f && h < 0.98f) ? 1 : 0;
    s += bits[j];
    qidx[b * NTOK + t * 4 + j] = -1;
    eidx[b * NTOK + t * 4 + j] = -1;
  }
  int sw = s;
#pragma unroll
  for (int d = 1; d < 64; d <<= 1) sw += __shfl_xor(sw, d);
  const int l = t & 63, w = t >> 6;
  if (l == 0) wsum[w] = sw;
  if (t == 0) { scntE = 0; scntZ = 0; }
  __syncthreads();
  if (t == 0) { int a = 0; for (int i = 0; i < 16; ++i) a += wsum[i]; stot = a; }
  __syncthreads();
  const bool fb = stot < 64;     // fallback: route everything to attention
#pragma unroll
  for (int j = 0; j < 4; ++j) {
    int e = fb ? 1 : bits[j];
    edge[b * NTOK + t * 4 + j] = e;
    if (e) {
      int p = atomicAdd(&scntE, 1);
      qidx[b * NTOK + p] = t * 4 + j;
    } else {
      int p = atomicAdd(&scntZ, 1);
      eidx[b * NTOK + p] = t * 4 + j;
    }
  }
  __syncthreads();
  if (t == 0) { cntE[b] = scntE; cntZ[b] = scntZ; }
}

// ---------------- LayerNorm (writes ln bf16) + x->bf16 ----------------
__global__ __launch_bounds__(256) void ln_kernel(
    const float* __restrict__ x, const float* __restrict__ gam,
    const float* __restrict__ bet, u16* __restrict__ lnb, u16* __restrict__ xb)
{
  const int row = blockIdx.x, t = threadIdx.x;
  const float* xr = x + (size_t)row * CDIM;
  float v[3];
#pragma unroll
  for (int j = 0; j < 3; ++j) v[j] = xr[t + j * 256];
  float s = v[0] + v[1] + v[2];
  float ss = v[0] * v[0] + v[1] * v[1] + v[2] * v[2];
#pragma unroll
  for (int d = 1; d < 64; d <<= 1) { s += __shfl_xor(s, d); ss += __shfl_xor(ss, d); }
  __shared__ float red[8];
  const int l = t & 63, w = t >> 6;
  if (l == 0) { red[w * 2] = s; red[w * 2 + 1] = ss; }
  __syncthreads();
  s = red[0] + red[2] + red[4] + red[6];
  ss = red[1] + red[3] + red[5] + red[7];
  const float mu = s * (1.f / 768.f);
  const float rstd = rsqrtf(ss * (1.f / 768.f) - mu * mu + 1e-5f);
#pragma unroll
  for (int j = 0; j < 3; ++j) {
    const int cc = t + j * 256;
    lnb[(size_t)row * CDIM + cc] = f2bf((v[j] - mu) * rstd * gam[cc] + bet[cc]);
    xb[(size_t)row * CDIM + cc] = f2bf(v[j]);
  }
}

// ---------------- fused fp32 [K,N] -> bf16 [N,K] transposes (4 weights) ----------------
__global__ __launch_bounds__(256) void transpose_all_kernel(
    const float* __restrict__ qkv_w, const float* __restrict__ proj_w,
    const float* __restrict__ fc1_w, const float* __restrict__ fc2_w,
    u16* __restrict__ qkvT, u16* __restrict__ projT,
    u16* __restrict__ fc1T, u16* __restrict__ fc2T)
{
  __shared__ float tile[32][33];
  int bid = blockIdx.x;
  const float* in; u16* outp; int K, N, bx, by;
  if (bid < 1728)      { in = qkv_w;  outp = qkvT; K = 768;  N = 2304; bx = bid % 72; by = bid / 72; }
  else if (bid < 2304) { bid -= 1728; in = proj_w; outp = projT; K = 768;  N = 768;  bx = bid % 24; by = bid / 24; }
  else if (bid < 3456) { bid -= 2304; in = fc1_w;  outp = fc1T; K = 768;  N = 1536; bx = bid % 48; by = bid / 48; }
  else                 { bid -= 3456; in = fc2_w;  outp = fc2T; K = 1536; N = 768;  bx = bid % 24; by = bid / 24; }
  const int tx = threadIdx.x & 31, ty = threadIdx.x >> 5;
#pragma unroll
  for (int j = 0; j < 32; j += 8)
    tile[ty + j][tx] = in[(size_t)(by * 32 + ty + j) * N + bx * 32 + tx];
  __syncthreads();
#pragma unroll
  for (int j = 0; j < 32; j += 8)
    outp[(size_t)(bx * 32 + ty + j) * K + by * 32 + tx] = f2bf(tile[tx][ty + j]);
}

// ---------------- bf16 MFMA GEMM with optional row gather/scatter ----------------
// EPI: 0 = +bias -> bf16 (compact out); 1 = +bias+resid -> f32 (scatter out);
//      2 = gelu(gelu(+bias)) -> bf16 (compact out); 3 = +bias -> f32 (scatter out)
template <int EPI, bool GATHER_A, bool SCATTER_OUT>
__global__ __launch_bounds__(256) void gemm_bt(
    const u16* __restrict__ A, const u16* __restrict__ Bt,
    const float* __restrict__ bias, const float* __restrict__ resid,
    const int* __restrict__ list, void* __restrict__ outp, int N, int K)
{
  const int bm = blockIdx.x, bn = blockIdx.y;
  const int b = bm >> 5, bmi = bm & 31;
  const int rb = bmi * 128;                         // position base within batch
  if (list[b * NTOK + rb] < 0) return;              // whole block beyond count

  __shared__ __align__(16) u16 lA[128 * 32];
  __shared__ __align__(16) u16 lB[128 * 32];
  const int t = threadIdx.x;
  const int l = t & 63, w = t >> 6;
  const int g = l >> 4, c = l & 15;
  const int wr = w >> 1, wc = w & 1;

  f32x4 acc[4][4];
#pragma unroll
  for (int i = 0; i < 4; ++i)
#pragma unroll
    for (int j = 0; j < 4; ++j) acc[i][j] = f32x4{0.f, 0.f, 0.f, 0.f};

  const int srow = t >> 2;                      // 0..63
  const int sslot = (t & 3) ^ (srow & 3);       // pre-swizzled source slot
  int ta0, ta1;
  if constexpr (GATHER_A) {
    ta0 = list[b * NTOK + rb + srow];       if (ta0 < 0) ta0 = 0;
    ta1 = list[b * NTOK + rb + 64 + srow];  if (ta1 < 0) ta1 = 0;
  } else {
    ta0 = rb + srow;
    ta1 = rb + 64 + srow;
  }
  const u16* gA0 = A + ((size_t)b * NTOK + ta0) * K + sslot * 8;
  const u16* gA1 = A + ((size_t)b * NTOK + ta1) * K + sslot * 8;
  const u16* gB0 = Bt + (size_t)(bn * 128 + srow) * K + sslot * 8;
  const u16* gB1 = Bt + (size_t)(bn * 128 + 64 + srow) * K + sslot * 8;
  char* ldA = (char*)lA + w * 1024;
  char* ldB = (char*)lB + w * 1024;

  for (int k0 = 0; k0 < K; k0 += 32) {
    __syncthreads();
    gload_lds16(gA0 + k0, ldA);
    gload_lds16(gA1 + k0, ldA + 4096);
    gload_lds16(gB0 + k0, ldB);
    gload_lds16(gB1 + k0, ldB + 4096);
    __syncthreads();
    short8 af[4], bfr[4];
#pragma unroll
    for (int mi = 0; mi < 4; ++mi) {
      int row = wr * 64 + mi * 16 + c;
      af[mi] = *(const short8*)((const char*)lA + row * 64 + ((g ^ (row & 3)) << 4));
    }
#pragma unroll
    for (int ni = 0; ni < 4; ++ni) {
      int row = wc * 64 + ni * 16 + c;
      bfr[ni] = *(const short8*)((const char*)lB + row * 64 + ((g ^ (row & 3)) << 4));
    }
#pragma unroll
    for (int mi = 0; mi < 4; ++mi)
#pragma unroll
      for (int ni = 0; ni < 4; ++ni)
        acc[mi][ni] = __builtin_amdgcn_mfma_f32_16x16x32_bf16(af[mi], bfr[ni], acc[mi][ni], 0, 0, 0);
  }

#pragma unroll
  for (int mi = 0; mi < 4; ++mi) {
#pragma unroll
    for (int ni = 0; ni < 4; ++ni) {
      const int col = bn * 128 + wc * 64 + ni * 16 + c;
      const float bv = bias[col];
      const int prow0 = rb + wr * 64 + mi * 16 + g * 4;
#pragma unroll
      for (int r = 0; r < 4; ++r) {
        float v = acc[mi][ni][r] + bv;
        int orow;
        if constexpr (SCATTER_OUT) {
          int tok = list[b * NTOK + prow0 + r];
          if (tok < 0) continue;
          orow = tok;
        } else {
          orow = prow0 + r;
        }
        const size_t idx = ((size_t)b * NTOK + orow) * N + col;
        if constexpr (EPI == 0) {
          ((u16*)outp)[idx] = f2bf(v);
        } else if constexpr (EPI == 1) {
          ((float*)outp)[idx] = v + resid[idx];
        } else if constexpr (EPI == 2) {
          ((u16*)outp)[idx] = f2bf(gelu_exact(gelu_exact(v)));
        } else {
          ((float*)outp)[idx] = v;
        }
      }
    }
  }
}

// ---------------- flash attention partials: swapped S^T, dbuf K/V, defer-max ----------------
// grid (32 qblocks, 24 bh, NSPLIT); partials: unnormalized O (bf16) + (m2,l) base-2
__global__ __launch_bounds__(256) void flash_part_kernel(
    const u16* __restrict__ qkv, const int* __restrict__ cntE,
    u16* __restrict__ partO, float2* __restrict__ partML)
{
  const int qt = blockIdx.x;
  const int bh = blockIdx.y;
  const int sp = blockIdx.z;
  const int b = bh / NHEAD, h = bh % NHEAD;
  const int cnt = cntE[b];
  if (qt * 128 >= cnt) return;

  const int ntiles = (cnt + 63) >> 6;
  const int per = (ntiles + NSPLIT - 1) / NSPLIT;
  const int tA = sp * per;
  const int tB = min(ntiles, tA + per);
  if (tA >= tB) return;
  const int tBf = min(tB, cnt >> 6);   // end of unmasked (full) tiles
  const int rem = cnt & 63;            // keys valid in the single partial tile

  __shared__ __align__(16) u16 lK[2][64 * 64];   // [key][dim], source-swizzled
  __shared__ __align__(16) u16 lV[2][64 * 64];   // [dim][key], swizzled
  __shared__ __align__(16) u16 lP[4][32 * 64];   // per-wave P^T bounce [q][key], swizzled

  const int t = threadIdx.x;
  const int l = t & 63, w = t >> 6;
  const int g = l >> 4, c = l & 15;
  const int kp = t & 31, db = t >> 5;            // V staging: key-pair, d-block
  const size_t tokbase = (size_t)b * NTOK;

  // Q fragments (B-operand): lane holds q = qbase + mi*16 + c, d-slice kb*32+g*8
  short8 qf[2][2];
#pragma unroll
  for (int mi = 0; mi < 2; ++mi) {
    const int pos = qt * 128 + w * 32 + mi * 16 + c;
    const u16* qp = qkv + (tokbase + pos) * QKVD + h * 64;
#pragma unroll
    for (int kb = 0; kb < 2; ++kb)
      qf[mi][kb] = *(const short8*)(qp + kb * 32 + g * 8);
  }

  f32x4 oacc[2][4];            // O^T: [mi(q)][nd(d)]: lane (g,c): d=nd*16+g*4+r, q=mi*16+c
  float m2run[2], lrun[2];     // m2run in RAW score units
#pragma unroll
  for (int mi = 0; mi < 2; ++mi) {
#pragma unroll
    for (int nd = 0; nd < 4; ++nd) oacc[mi][nd] = f32x4{0.f, 0.f, 0.f, 0.f};
    m2run[mi] = -1e30f; lrun[mi] = 0.f;
  }

  char* lPw = (char*)lP[w];

  auto stageK = [&](int kt, int buf) {
#pragma unroll
    for (int j = 0; j < 2; ++j) {
      int seg = j * 256 + t;
      int row = seg >> 3;
      int sl = (seg & 7) ^ (row & 7);
      gload_lds16(qkv + (tokbase + kt * 64 + row) * QKVD + CDIM + h * 64 + sl * 8,
                  (char*)lK[buf] + j * 4096 + w * 1024);
    }
  };
  uint4 va, vb;
  auto loadV = [&](int kt) {
    const u16* vg = qkv + (tokbase + kt * 64 + kp * 2) * QKVD + 2 * CDIM + h * 64 + db * 8;
    va = *(const uint4*)vg;
    vb = *(const uint4*)(vg + QKVD);
  };
  auto writeV = [&](int buf) {
    union { uint4 q; u16 s[8]; } u0, u1; u0.q = va; u1.q = vb;
    char* lvb = (char*)lV[buf];
#pragma unroll
    for (int j = 0; j < 8; ++j) {
      int d = db * 8 + j;
      unsigned pk = (unsigned)u0.s[j] | ((unsigned)u1.s[j] << 16);
      *(unsigned*)(lvb + d * 128 + ((kp * 4) ^ ((d & 7) << 4))) = pk;
    }
  };

  int cur = 0;
  stageK(tA, 0);
  loadV(tA);
  writeV(0);
  __syncthreads();

#define FLASH_TILE(MASKED)                                                        \
  {                                                                               \
    const bool hasNext = (kt + 1 < tB);                                           \
    if (hasNext) { stageK(kt + 1, cur ^ 1); loadV(kt + 1); }                      \
    const char* lKc = (const char*)lK[cur];                                       \
    short8 kf[4][2];                                                              \
    _Pragma("unroll")                                                             \
    for (int ni = 0; ni < 4; ++ni) {                                              \
      int row = ni * 16 + c;                                                      \
      _Pragma("unroll")                                                           \
      for (int kb = 0; kb < 2; ++kb)                                              \
        kf[ni][kb] = *(const short8*)(lKc + row * 128 +                           \
                                      (((kb * 4 + g) ^ (row & 7)) << 4));         \
    }                                                                             \
    f32x4 st[2][4];                                                               \
    __builtin_amdgcn_s_setprio(1);                                                \
    _Pragma("unroll")                                                             \
    for (int mi = 0; mi < 2; ++mi)                                                \
      _Pragma("unroll")                                                           \
      for (int ni = 0; ni < 4; ++ni) {                                            \
        f32x4 sv = f32x4{0.f, 0.f, 0.f, 0.f};                                     \
        sv = __builtin_amdgcn_mfma_f32_16x16x32_bf16(kf[ni][0], qf[mi][0], sv, 0, 0, 0); \
        sv = __builtin_amdgcn_mfma_f32_16x16x32_bf16(kf[ni][1], qf[mi][1], sv, 0, 0, 0); \
        st[mi][ni] = sv;                                                          \
      }                                                                           \
    __builtin_amdgcn_s_setprio(0);                                                \
    if (MASKED) {                                                                 \
      _Pragma("unroll")                                                           \
      for (int mi = 0; mi < 2; ++mi)                                              \
        _Pragma("unroll")                                                         \
        for (int ni = 0; ni < 4; ++ni)                                            \
          _Pragma("unroll")                                                       \
          for (int r = 0; r < 4; ++r)                                             \
            if (ni * 16 + g * 4 + r >= rem) st[mi][ni][r] = -1e30f;               \
    }                                                                             \
    _Pragma("unroll")                                                             \
    for (int mi = 0; mi < 2; ++mi) {                                              \
      float mx = fmaxf(                                                           \
          fmaxf(fmaxf(fmaxf(st[mi][0][0], st[mi][0][1]), fmaxf(st[mi][0][2], st[mi][0][3])), \
                fmaxf(fmaxf(st[mi][1][0], st[mi][1][1]), fmaxf(st[mi][1][2], st[mi][1][3]))), \
          fmaxf(fmaxf(fmaxf(st[mi][2][0], st[mi][2][1]), fmaxf(st[mi][2][2], st[mi][2][3])), \
                fmaxf(fmaxf(st[mi][3][0], st[mi][3][1]), fmaxf(st[mi][3][2], st[mi][3][3])))); \
      mx = fmaxf(mx, __shfl_xor(mx, 16));                                         \
      mx = fmaxf(mx, __shfl_xor(mx, 32));                                         \
      if (!__all(mx - m2run[mi] <= THRRAW)) {                                     \
        const float mnew = fmaxf(m2run[mi], mx);                                  \
        const float alpha = fast_exp2((m2run[mi] - mnew) * SCALE2);               \
        m2run[mi] = mnew;                                                         \
        lrun[mi] *= alpha;                                                        \
        _Pragma("unroll")                                                         \
        for (int nd = 0; nd < 4; ++nd)                                            \
          _Pragma("unroll")                                                       \
          for (int r = 0; r < 4; ++r) oacc[mi][nd][r] *= alpha;                   \
      }                                                                           \
      const float msc = m2run[mi] * SCALE2;                                       \
      float rs = 0.f;                                                             \
      const int qrow = mi * 16 + c;                                               \
      char* pbase = lPw + qrow * 128;                                             \
      const int swz = (qrow & 7) << 4;                                            \
      _Pragma("unroll")                                                           \
      for (int ni = 0; ni < 4; ++ni) {                                            \
        float p0 = fast_exp2(fmaf(st[mi][ni][0], SCALE2, -msc));                  \
        float p1 = fast_exp2(fmaf(st[mi][ni][1], SCALE2, -msc));                  \
        float p2 = fast_exp2(fmaf(st[mi][ni][2], SCALE2, -msc));                  \
        float p3 = fast_exp2(fmaf(st[mi][ni][3], SCALE2, -msc));                  \
        rs += (p0 + p1) + (p2 + p3);                                              \
        *(uint2*)(pbase + ((ni * 32 + g * 8) ^ swz)) =                            \
            make_uint2(cvtpk(p0, p1), cvtpk(p2, p3));                             \
      }                                                                           \
      rs += __shfl_xor(rs, 16);                                                   \
      rs += __shfl_xor(rs, 32);                                                   \
      lrun[mi] += rs;                                                             \
    }                                                                             \
    const char* lVc = (const char*)lV[cur];                                       \
    _Pragma("unroll")                                                             \
    for (int kb = 0; kb < 2; ++kb) {                                              \
      short8 pb[2], vf[4];                                                        \
      _Pragma("unroll")                                                           \
      for (int mi = 0; mi < 2; ++mi) {                                            \
        int qrow = mi * 16 + c;                                                   \
        pb[mi] = *(const short8*)(lPw + qrow * 128 +                              \
                                  ((kb * 64 + g * 16) ^ ((qrow & 7) << 4)));      \
      }                                                                           \
      _Pragma("unroll")                                                           \
      for (int nd = 0; nd < 4; ++nd) {                                            \
        int d = nd * 16 + c;                                                      \
        vf[nd] = *(const short8*)(lVc + d * 128 +                                 \
                                  (((kb * 4 + g) ^ (d & 7)) << 4));               \
      }                                                                           \
      __builtin_amdgcn_s_setprio(1);                                              \
      _Pragma("unroll")                                                           \
      for (int mi = 0; mi < 2; ++mi)                                              \
        _Pragma("unroll")                                                         \
        for (int nd = 0; nd < 4; ++nd)                                            \
          oacc[mi][nd] = __builtin_amdgcn_mfma_f32_16x16x32_bf16(vf[nd], pb[mi], oacc[mi][nd], 0, 0, 0); \
      __builtin_amdgcn_s_setprio(0);                                              \
    }                                                                             \
    if (hasNext) writeV(cur ^ 1);                                                 \
    __syncthreads();                                                              \
    cur ^= 1;                                                                     \
  }

  int kt = tA;
  for (; kt < tBf; ++kt) FLASH_TILE(0)
  for (; kt < tB; ++kt) FLASH_TILE(1)
#undef FLASH_TILE

  // ---- store partials: O^T lane (g,c): q=mi*16+c, d=nd*16+g*4+r; m stored base-2 ----
  const size_t pobase = ((size_t)(sp * 2 + b) * NHEAD + h) * NTOK;
#pragma unroll
  for (int mi = 0; mi < 2; ++mi) {
    const int pos = qt * 128 + w * 32 + mi * 16 + c;
    if (pos < cnt) {
      u16* op = partO + (pobase + pos) * 64;
#pragma unroll
      for (int nd = 0; nd < 4; ++nd) {
        ushort4 pk4;
        pk4.x = f2bf(oacc[mi][nd][0]);
        pk4.y = f2bf(oacc[mi][nd][1]);
        pk4.z = f2bf(oacc[mi][nd][2]);
        pk4.w = f2bf(oacc[mi][nd][3]);
        *(ushort4*)(op + nd * 16 + g * 4) = pk4;
      }
      if (g == 0)
        partML[pobase + pos] = make_float2(m2run[mi] * SCALE2, lrun[mi]);
    }
  }
}

// ---------------- merge split partials -> compact obf (bf16) ----------------
__global__ __launch_bounds__(256) void flash_merge_kernel(
    const u16* __restrict__ partO, const float2* __restrict__ partML,
    const int* __restrict__ cntE, u16* __restrict__ obf)
{
  const int bh = blockIdx.y;
  const int b = bh / NHEAD, h = bh % NHEAD;
  const int t = threadIdx.x;
  const int pos = blockIdx.x * 4 + (t >> 6);
  const int d = t & 63;
  const int cnt = cntE[b];
  if (pos >= cnt) return;
  const int ntiles = (cnt + 63) >> 6;
  const int per = (ntiles + NSPLIT - 1) / NSPLIT;

  float2 ml[NSPLIT];
  float M = -3e38f;
#pragma unroll
  for (int sp = 0; sp < NSPLIT; ++sp) {
    if (sp * per < ntiles) {
      ml[sp] = partML[((size_t)(sp * 2 + b) * NHEAD + h) * NTOK + pos];
      M = fmaxf(M, ml[sp].x);
    }
  }
  float L = 0.f, O = 0.f;
#pragma unroll
  for (int sp = 0; sp < NSPLIT; ++sp) {
    if (sp * per < ntiles) {
      const float e = fast_exp2(ml[sp].x - M);
      L += ml[sp].y * e;
      O += e * bf2f(partO[(((size_t)(sp * 2 + b) * NHEAD + h) * NTOK + pos) * 64 + d]);
    }
  }
  obf[((size_t)b * NTOK + pos) * CDIM + h * 64 + d] = f2bf(O / L);
}

// ---------------- masked mean pool partials ----------------
__global__ __launch_bounds__(256) void pool_partial_kernel(
    const float* __restrict__ h2, const int* __restrict__ edge, float* __restrict__ pooled)
{
  const int bid = blockIdx.x;                 // 96 = b*48 + cg*16 + ts
  const int b = bid / 48, rm = bid % 48;
  const int cg = rm / 16, ts = rm % 16;
  const int ch = cg * 256 + threadIdx.x;
  float s = 0.f;
  for (int tok = ts * 256; tok < ts * 256 + 256; ++tok) {
    if (!edge[b * NTOK + tok])
      s += h2[((size_t)b * NTOK + tok) * CDIM + ch];
  }
  atomicAdd(&pooled[b * CDIM + ch], s);
}

// ---------------- ECA conv(5) + sigmoid ----------------
__global__ void eca_kernel(const float* __restrict__ pooled, const float* __restrict__ w5,
                           const int* __restrict__ ecnt, float* __restrict__ gate)
{
  const int b = blockIdx.x, c = threadIdx.x;
  const float inv = 1.f / fmaxf((float)ecnt[b], 1.f);
  float a = 0.f;
#pragma unroll
  for (int j = 0; j < 5; ++j) {
    int i = c - 2 + j;
    if (i >= 0 && i < CDIM) a += w5[j] * pooled[b * CDIM + i];
  }
  a *= inv;
  gate[b * CDIM + c] = 1.f / (1.f + __expf(-a));
}

// ---------------- final scatter-combine ----------------
__global__ __launch_bounds__(256) void combine_kernel(
    const float* __restrict__ x, const float* __restrict__ attn,
    const float* __restrict__ h2, const float* __restrict__ gate,
    const int* __restrict__ edge, float* __restrict__ out)
{
  const size_t i = ((size_t)blockIdx.x * 256 + threadIdx.x) * 4;
  const int b = (int)(i / ((size_t)NTOK * CDIM));
  const size_t r = i % ((size_t)NTOK * CDIM);
  const int tok = (int)(r / CDIM);
  const int cc = (int)(r % CDIM);
  float4 ov;
  if (edge[b * NTOK + tok]) {
    ov = *(const float4*)(attn + i);
  } else {
    float4 xv = *(const float4*)(x + i);
    float4 hv = *(const float4*)(h2 + i);
    float4 gv = *(const float4*)(gate + b * CDIM + cc);
    ov.x = xv.x + hv.x * gv.x;
    ov.y = xv.y + hv.y * gv.y;
    ov.z = xv.z + hv.z * gv.z;
    ov.w = xv.w + hv.w * gv.w;
  }
  *(float4*)(out + i) = ov;
}

extern "C" void kernel_launch(void* const* d_in, const int* in_sizes, int n_in,
                              void* d_out, int out_size, void* d_ws, size_t ws_size,
                              hipStream_t stream) {
  const float* x      = (const float*)d_in[0];
  const float* ah     = (const float*)d_in[1];
  const float* qkv_w  = (const float*)d_in[2];
  const float* qkv_b  = (const float*)d_in[3];
  const float* proj_w = (const float*)d_in[4];
  const float* proj_b = (const float*)d_in[5];
  const float* ln_g   = (const float*)d_in[6];
  const float* ln_b   = (const float*)d_in[7];
  const float* fc1_w  = (const float*)d_in[8];
  const float* fc1_b  = (const float*)d_in[9];
  const float* fc2_w  = (const float*)d_in[10];
  const float* fc2_b  = (const float*)d_in[11];
  const float* eca_w  = (const float*)d_in[12];
  float* out = (float*)d_out;

  char* ws = (char*)d_ws;
  size_t off = 0;
  auto alloc = [&](size_t bytes) {
    char* p = ws + off;
    off += (bytes + 255) & ~(size_t)255;
    return p;
  };
  float* hint   = (float*)alloc((size_t)2 * NTOK * 4);
  int*   edge   = (int*)alloc((size_t)2 * NTOK * 4);
  int*   qidx   = (int*)alloc((size_t)2 * NTOK * 4);
  int*   eidx   = (int*)alloc((size_t)2 * NTOK * 4);
  int*   cntE   = (int*)alloc(256);
  int*   cntZ   = (int*)alloc(256);
  u16*   xbf    = (u16*)alloc((size_t)2 * NTOK * CDIM * 2);
  u16*   lnbf   = (u16*)alloc((size_t)2 * NTOK * CDIM * 2);
  u16*   qkvT   = (u16*)alloc((size_t)QKVD * CDIM * 2);
  u16*   projT  = (u16*)alloc((size_t)CDIM * CDIM * 2);
  u16*   fc1T   = (u16*)alloc((size_t)1536 * CDIM * 2);
  u16*   fc2T   = (u16*)alloc((size_t)CDIM * 1536 * 2);
  u16*   qkvb   = (u16*)alloc((size_t)2 * NTOK * QKVD * 2);
  u16*   obf    = (u16*)alloc((size_t)2 * NTOK * CDIM * 2);
  u16*   h1bf   = (u16*)alloc((size_t)2 * NTOK * 1536 * 2);   // 25.17 MB
  float* h2     = (float*)alloc((size_t)2 * NTOK * CDIM * 4); // 25.17 MB (contiguous after h1bf)
  float* attn   = (float*)alloc((size_t)2 * NTOK * CDIM * 4);
  float* pooled = (float*)alloc((size_t)2 * CDIM * 4);
  float* gate   = (float*)alloc((size_t)2 * CDIM * 4);
  // Aliased scratch (lifetimes disjoint, stream-ordered):
  //  partO (50.33 MB) over h1bf+h2: dead before fc1 writes h1bf.
  //  partML (3.15 MB) over attn: dead before proj writes attn.
  u16*   partO  = (u16*)h1bf;
  float* partML = attn;

  pool_hint_kernel<<<dim3(128), 256, 0, stream>>>(ah, hint);
  finalize_edge_kernel<<<dim3(2), 1024, 0, stream>>>(hint, edge, qidx, eidx, cntE, cntZ);
  ln_kernel<<<dim3(8192), 256, 0, stream>>>(x, ln_g, ln_b, lnbf, xbf);
  transpose_all_kernel<<<dim3(4608), 256, 0, stream>>>(
      qkv_w, proj_w, fc1_w, fc2_w, qkvT, projT, fc1T, fc2T);

  // qkv: gather edge rows -> compact qkvb
  gemm_bt<0, true, false><<<dim3(64, 18), 256, 0, stream>>>(
      xbf, qkvT, qkv_b, nullptr, qidx, qkvb, 2304, 768);
  // flash over compact rows, split-K partials + merge
  flash_part_kernel<<<dim3(32, 24, NSPLIT), 256, 0, stream>>>(qkvb, cntE, partO, (float2*)partML);
  flash_merge_kernel<<<dim3(1024, 24), 256, 0, stream>>>(partO, (const float2*)partML, cntE, obf);
  // proj: direct compact A, scatter to full attn (+resid x)
  gemm_bt<1, false, true><<<dim3(64, 6), 256, 0, stream>>>(
      obf, projT, proj_b, x, qidx, attn, 768, 768);
  // fc1: gather easy rows -> compact h1
  gemm_bt<2, true, false><<<dim3(64, 12), 256, 0, stream>>>(
      lnbf, fc1T, fc1_b, nullptr, eidx, h1bf, 1536, 768);
  // fc2: direct compact A, scatter to full h2
  gemm_bt<3, false, true><<<dim3(64, 6), 256, 0, stream>>>(
      h1bf, fc2T, fc2_b, nullptr, eidx, h2, 768, 1536);

  hipMemsetAsync(pooled, 0, (size_t)2 * CDIM * 4, stream);
  pool_partial_kernel<<<dim3(96), 256, 0, stream>>>(h2, edge, pooled);
  eca_kernel<<<dim3(2), 768, 0, stream>>>(pooled, eca_w, cntZ, gate);
  combine_kernel<<<dim3(6144), 256, 0, stream>>>(x, attn, h2, gate, edge, out);
}

// Round 6
// 461.806 us; speedup vs baseline: 1.1982x; 1.0924x over previous
//
#include <hip/hip_runtime.h>

using u16 = unsigned short;
using short8 = __attribute__((ext_vector_type(8))) short;
using f32x4 = __attribute__((ext_vector_type(4))) float;

#define NTOK 4096
#define CDIM 768
#define QKVD 2304
#define NHEAD 12
#define NSPLIT 4
// 0.125 (1/sqrt(64)) * log2(e)
#define SCALE2 0.18033688011112042f
// defer-max threshold: 8 (base-2) in raw-score units = 8/SCALE2
#define THRRAW 44.3614195558f

__device__ __forceinline__ u16 f2bf(float f) {
  unsigned u = __float_as_uint(f);
  u += 0x7FFFu + ((u >> 16) & 1u);
  return (u16)(u >> 16);
}
__device__ __forceinline__ float bf2f(u16 v) {
  return __uint_as_float(((unsigned)v) << 16);
}
__device__ __forceinline__ float fast_exp2(float x) {
  float r;
  asm("v_exp_f32 %0, %1" : "=v"(r) : "v"(x));
  return r;
}
__device__ __forceinline__ unsigned cvtpk(float lo, float hi) {
  unsigned r;
  asm("v_cvt_pk_bf16_f32 %0, %1, %2" : "=v"(r) : "v"(lo), "v"(hi));
  return r;
}

__device__ __forceinline__ void gload_lds16(const void* g, void* l) {
  __builtin_amdgcn_global_load_lds(
      (__attribute__((address_space(1))) void*)g,
      (__attribute__((address_space(3))) void*)l, 16u, 0, 0u);
}

__device__ __forceinline__ float gelu_exact(float z) {
  return 0.5f * z * (1.0f + erff(z * 0.70710678118654752f));
}

// ---------------- edge mask: pool 16x16 blocks of alpha_hint ----------------
__global__ __launch_bounds__(256) void pool_hint_kernel(
    const float* __restrict__ ah, float* __restrict__ hint)
{
  const int bid = blockIdx.x;            // B*64 blocks: (b, cellrow)
  const int b = bid >> 6, cr = bid & 63;
  const int t = threadIdx.x;
  const float* base = ah + ((size_t)b * 1024 + (size_t)cr * 16) * 1024;
  float s = 0.f;
#pragma unroll
  for (int pr = 0; pr < 16; ++pr) {
    float4 v = *(const float4*)(base + (size_t)pr * 1024 + t * 4);
    s += v.x + v.y + v.z + v.w;
  }
  s += __shfl_xor(s, 1);
  s += __shfl_xor(s, 2);
  if ((t & 3) == 0)
    hint[b * NTOK + cr * 64 + (t >> 2)] = s * (1.f / 256.f);
}

__global__ __launch_bounds__(1024) void finalize_edge_kernel(
    const float* __restrict__ hint, int* __restrict__ edge,
    int* __restrict__ qidx, int* __restrict__ eidx,
    int* __restrict__ cntE, int* __restrict__ cntZ)
{
  const int b = blockIdx.x, t = threadIdx.x;
  __shared__ int wsum[16];
  __shared__ int scntE, scntZ, stot;
  int bits[4]; int s = 0;
#pragma unroll
  for (int j = 0; j < 4; ++j) {
    float h = hint[b * NTOK + t * 4 + j];
    bits[j] = (h > 0.02f && h < 0.98f) ? 1 : 0;
    s += bits[j];
    qidx[b * NTOK + t * 4 + j] = -1;
    eidx[b * NTOK + t * 4 + j] = -1;
  }
  int sw = s;
#pragma unroll
  for (int d = 1; d < 64; d <<= 1) sw += __shfl_xor(sw, d);
  const int l = t & 63, w = t >> 6;
  if (l == 0) wsum[w] = sw;
  if (t == 0) { scntE = 0; scntZ = 0; }
  __syncthreads();
  if (t == 0) { int a = 0; for (int i = 0; i < 16; ++i) a += wsum[i]; stot = a; }
  __syncthreads();
  const bool fb = stot < 64;     // fallback: route everything to attention
#pragma unroll
  for (int j = 0; j < 4; ++j) {
    int e = fb ? 1 : bits[j];
    edge[b * NTOK + t * 4 + j] = e;
    if (e) {
      int p = atomicAdd(&scntE, 1);
      qidx[b * NTOK + p] = t * 4 + j;
    } else {
      int p = atomicAdd(&scntZ, 1);
      eidx[b * NTOK + p] = t * 4 + j;
    }
  }
  __syncthreads();
  if (t == 0) { cntE[b] = scntE; cntZ[b] = scntZ; }
}

// ---------------- LayerNorm (writes ln bf16) + x->bf16 ----------------
__global__ __launch_bounds__(256) void ln_kernel(
    const float* __restrict__ x, const float* __restrict__ gam,
    const float* __restrict__ bet, u16* __restrict__ lnb, u16* __restrict__ xb)
{
  const int row = blockIdx.x, t = threadIdx.x;
  const float* xr = x + (size_t)row * CDIM;
  float v[3];
#pragma unroll
  for (int j = 0; j < 3; ++j) v[j] = xr[t + j * 256];
  float s = v[0] + v[1] + v[2];
  float ss = v[0] * v[0] + v[1] * v[1] + v[2] * v[2];
#pragma unroll
  for (int d = 1; d < 64; d <<= 1) { s += __shfl_xor(s, d); ss += __shfl_xor(ss, d); }
  __shared__ float red[8];
  const int l = t & 63, w = t >> 6;
  if (l == 0) { red[w * 2] = s; red[w * 2 + 1] = ss; }
  __syncthreads();
  s = red[0] + red[2] + red[4] + red[6];
  ss = red[1] + red[3] + red[5] + red[7];
  const float mu = s * (1.f / 768.f);
  const float rstd = rsqrtf(ss * (1.f / 768.f) - mu * mu + 1e-5f);
#pragma unroll
  for (int j = 0; j < 3; ++j) {
    const int cc = t + j * 256;
    lnb[(size_t)row * CDIM + cc] = f2bf((v[j] - mu) * rstd * gam[cc] + bet[cc]);
    xb[(size_t)row * CDIM + cc] = f2bf(v[j]);
  }
}

// ---------------- fused fp32 [K,N] -> bf16 [N,K] transposes (4 weights) ----------------
__global__ __launch_bounds__(256) void transpose_all_kernel(
    const float* __restrict__ qkv_w, const float* __restrict__ proj_w,
    const float* __restrict__ fc1_w, const float* __restrict__ fc2_w,
    u16* __restrict__ qkvT, u16* __restrict__ projT,
    u16* __restrict__ fc1T, u16* __restrict__ fc2T)
{
  __shared__ float tile[32][33];
  int bid = blockIdx.x;
  const float* in; u16* outp; int K, N, bx, by;
  if (bid < 1728)      { in = qkv_w;  outp = qkvT; K = 768;  N = 2304; bx = bid % 72; by = bid / 72; }
  else if (bid < 2304) { bid -= 1728; in = proj_w; outp = projT; K = 768;  N = 768;  bx = bid % 24; by = bid / 24; }
  else if (bid < 3456) { bid -= 2304; in = fc1_w;  outp = fc1T; K = 768;  N = 1536; bx = bid % 48; by = bid / 48; }
  else                 { bid -= 3456; in = fc2_w;  outp = fc2T; K = 1536; N = 768;  bx = bid % 24; by = bid / 24; }
  const int tx = threadIdx.x & 31, ty = threadIdx.x >> 5;
#pragma unroll
  for (int j = 0; j < 32; j += 8)
    tile[ty + j][tx] = in[(size_t)(by * 32 + ty + j) * N + bx * 32 + tx];
  __syncthreads();
#pragma unroll
  for (int j = 0; j < 32; j += 8)
    outp[(size_t)(bx * 32 + ty + j) * K + by * 32 + tx] = f2bf(tile[tx][ty + j]);
}

// ---------------- bf16 MFMA GEMM with optional row gather/scatter ----------------
// EPI: 0 = +bias -> bf16 (compact out); 1 = +bias+resid -> f32 (scatter out);
//      2 = gelu(gelu(+bias)) -> bf16 (compact out); 3 = +bias -> f32 (scatter out)
// BN: 128 (wave = 64x64, 4x4 frags) or 64 (wave = 64x32, 4x2 frags)
template <int EPI, bool GATHER_A, bool SCATTER_OUT, int BN>
__global__ __launch_bounds__(256) void gemm_bt(
    const u16* __restrict__ A, const u16* __restrict__ Bt,
    const float* __restrict__ bias, const float* __restrict__ resid,
    const int* __restrict__ list, void* __restrict__ outp, int N, int K)
{
  constexpr int NN = BN / 32;                       // N-frags per wave
  const int bm = blockIdx.x, bn = blockIdx.y;
  const int b = bm >> 5, bmi = bm & 31;
  const int rb = bmi * 128;                         // position base within batch
  if (list[b * NTOK + rb] < 0) return;              // whole block beyond count

  __shared__ __align__(16) u16 lA[128 * 32];
  __shared__ __align__(16) u16 lB[BN * 32];
  const int t = threadIdx.x;
  const int l = t & 63, w = t >> 6;
  const int g = l >> 4, c = l & 15;
  const int wr = w >> 1, wc = w & 1;

  f32x4 acc[4][NN];
#pragma unroll
  for (int i = 0; i < 4; ++i)
#pragma unroll
    for (int j = 0; j < NN; ++j) acc[i][j] = f32x4{0.f, 0.f, 0.f, 0.f};

  const int srow = t >> 2;                      // 0..63
  const int sslot = (t & 3) ^ (srow & 3);       // pre-swizzled source slot
  int ta0, ta1;
  if constexpr (GATHER_A) {
    ta0 = list[b * NTOK + rb + srow];       if (ta0 < 0) ta0 = 0;
    ta1 = list[b * NTOK + rb + 64 + srow];  if (ta1 < 0) ta1 = 0;
  } else {
    ta0 = rb + srow;
    ta1 = rb + 64 + srow;
  }
  const u16* gA0 = A + ((size_t)b * NTOK + ta0) * K + sslot * 8;
  const u16* gA1 = A + ((size_t)b * NTOK + ta1) * K + sslot * 8;
  const u16* gB0 = Bt + (size_t)(bn * BN + srow) * K + sslot * 8;
  const u16* gB1 = (BN == 128) ? Bt + (size_t)(bn * BN + 64 + srow) * K + sslot * 8 : nullptr;
  char* ldA = (char*)lA + w * 1024;
  char* ldB = (char*)lB + w * 1024;

  for (int k0 = 0; k0 < K; k0 += 32) {
    __syncthreads();
    gload_lds16(gA0 + k0, ldA);
    gload_lds16(gA1 + k0, ldA + 4096);
    gload_lds16(gB0 + k0, ldB);
    if constexpr (BN == 128) gload_lds16(gB1 + k0, ldB + 4096);
    __syncthreads();
    short8 af[4], bfr[NN];
#pragma unroll
    for (int mi = 0; mi < 4; ++mi) {
      int row = wr * 64 + mi * 16 + c;
      af[mi] = *(const short8*)((const char*)lA + row * 64 + ((g ^ (row & 3)) << 4));
    }
#pragma unroll
    for (int ni = 0; ni < NN; ++ni) {
      int row = wc * (BN / 2) + ni * 16 + c;
      bfr[ni] = *(const short8*)((const char*)lB + row * 64 + ((g ^ (row & 3)) << 4));
    }
#pragma unroll
    for (int mi = 0; mi < 4; ++mi)
#pragma unroll
      for (int ni = 0; ni < NN; ++ni)
        acc[mi][ni] = __builtin_amdgcn_mfma_f32_16x16x32_bf16(af[mi], bfr[ni], acc[mi][ni], 0, 0, 0);
  }

#pragma unroll
  for (int mi = 0; mi < 4; ++mi) {
#pragma unroll
    for (int ni = 0; ni < NN; ++ni) {
      const int col = bn * BN + wc * (BN / 2) + ni * 16 + c;
      const float bv = bias[col];
      const int prow0 = rb + wr * 64 + mi * 16 + g * 4;
#pragma unroll
      for (int r = 0; r < 4; ++r) {
        float v = acc[mi][ni][r] + bv;
        int orow;
        if constexpr (SCATTER_OUT) {
          int tok = list[b * NTOK + prow0 + r];
          if (tok < 0) continue;
          orow = tok;
        } else {
          orow = prow0 + r;
        }
        const size_t idx = ((size_t)b * NTOK + orow) * N + col;
        if constexpr (EPI == 0) {
          ((u16*)outp)[idx] = f2bf(v);
        } else if constexpr (EPI == 1) {
          ((float*)outp)[idx] = v + resid[idx];
        } else if constexpr (EPI == 2) {
          ((u16*)outp)[idx] = f2bf(gelu_exact(gelu_exact(v)));
        } else {
          ((float*)outp)[idx] = v;
        }
      }
    }
  }
}

// ---------------- flash attention partials: barrier-free, 1 wave/block ----------------
// grid (128 qblocks of 32, 24 bh, NSPLIT); partials: unnormalized O (bf16) + (m2,l)
// K fragments load global->reg (pipelined 1 tile ahead, static sets);
// V loads at tile start -> transposed/swizzled write into this wave's own LDS.
// No __syncthreads anywhere: prefetches survive, waves fully independent.
__global__ __launch_bounds__(64) void flash_part_kernel(
    const u16* __restrict__ qkv, const int* __restrict__ cntE,
    u16* __restrict__ partO, float2* __restrict__ partML)
{
  const int qt = blockIdx.x;
  const int bh = blockIdx.y;
  const int sp = blockIdx.z;
  const int b = bh / NHEAD, h = bh % NHEAD;
  const int cnt = cntE[b];
  if (qt * 32 >= cnt) return;

  const int ntiles = (cnt + 63) >> 6;
  const int per = (ntiles + NSPLIT - 1) / NSPLIT;
  const int tA = sp * per;
  const int tB = min(ntiles, tA + per);
  if (tA >= tB) return;

  __shared__ __align__(16) u16 lV[64 * 64];      // this wave's V^T, swizzled (8KB)
  __shared__ __align__(16) u16 lP[32 * 64];      // this wave's P^T bounce (4KB)

  const int l = threadIdx.x;
  const int g = l >> 4, c = l & 15;
  const int kp = l & 31, dgr = (l >> 5) * 4;     // V staging: key-pair, d-block group
  const size_t tokbase = (size_t)b * NTOK;

  // Q fragments (B-operand): lane holds q = qt*32 + mi*16 + c, d-slice kb*32+g*8
  short8 qf[2][2];
#pragma unroll
  for (int mi = 0; mi < 2; ++mi) {
    const int pos = qt * 32 + mi * 16 + c;
    const u16* qp = qkv + (tokbase + pos) * QKVD + h * 64;
#pragma unroll
    for (int kb = 0; kb < 2; ++kb)
      qf[mi][kb] = *(const short8*)(qp + kb * 32 + g * 8);
  }

  f32x4 oacc[2][4];            // O^T: [mi(q)][nd(d)]: lane (g,c): d=nd*16+g*4+r, q=mi*16+c
  float m2run[2], lrun[2];     // m2run in RAW score units
#pragma unroll
  for (int mi = 0; mi < 2; ++mi) {
#pragma unroll
    for (int nd = 0; nd < 4; ++nd) oacc[mi][nd] = f32x4{0.f, 0.f, 0.f, 0.f};
    m2run[mi] = -1e30f; lrun[mi] = 0.f;
  }

  // K fragment register sets (A-operand): lane (c,g): K[key=ni*16+c][d=kb*32+g*8..+8]
  short8 kS0[4][2], kS1[4][2];

#define LOADK(KS, kt)                                                             \
  {                                                                               \
    const u16* kg = qkv + (tokbase + (kt) * 64 + c) * QKVD + CDIM + h * 64 + g * 8; \
    _Pragma("unroll")                                                             \
    for (int ni = 0; ni < 4; ++ni)                                                \
      _Pragma("unroll")                                                           \
      for (int kb = 0; kb < 2; ++kb)                                              \
        KS[ni][kb] = *(const short8*)(kg + (size_t)(ni * 16) * QKVD + kb * 32);   \
  }

#define FLASH_BODY(KS, kt)                                                        \
  {                                                                               \
    const bool msk = ((kt) * 64 + 64 > cnt);                                      \
    const int rem = cnt - (kt) * 64;                                              \
    /* V loads for this tile (latency hidden under QK + softmax) */               \
    uint4 vv[8];                                                                  \
    {                                                                             \
      const u16* vg = qkv + (tokbase + (kt) * 64 + kp * 2) * QKVD + 2 * CDIM + h * 64 + dgr * 8; \
      _Pragma("unroll")                                                           \
      for (int dbb = 0; dbb < 4; ++dbb) {                                         \
        vv[dbb]     = *(const uint4*)(vg + dbb * 8);                              \
        vv[4 + dbb] = *(const uint4*)(vg + QKVD + dbb * 8);                       \
      }                                                                           \
    }                                                                             \
    /* ---- S^T = K Q^T ---- */                                                   \
    f32x4 st[2][4];                                                               \
    __builtin_amdgcn_s_setprio(1);                                                \
    _Pragma("unroll")                                                             \
    for (int mi = 0; mi < 2; ++mi)                                                \
      _Pragma("unroll")                                                           \
      for (int ni = 0; ni < 4; ++ni) {                                            \
        f32x4 sv = f32x4{0.f, 0.f, 0.f, 0.f};                                     \
        sv = __builtin_amdgcn_mfma_f32_16x16x32_bf16(KS[ni][0], qf[mi][0], sv, 0, 0, 0); \
        sv = __builtin_amdgcn_mfma_f32_16x16x32_bf16(KS[ni][1], qf[mi][1], sv, 0, 0, 0); \
        st[mi][ni] = sv;                                                          \
      }                                                                           \
    __builtin_amdgcn_s_setprio(0);                                                \
    if (msk) {                                                                    \
      _Pragma("unroll")                                                           \
      for (int mi = 0; mi < 2; ++mi)                                              \
        _Pragma("unroll")                                                         \
        for (int ni = 0; ni < 4; ++ni)                                            \
          _Pragma("unroll")                                                       \
          for (int r = 0; r < 4; ++r)                                             \
            if (ni * 16 + g * 4 + r >= rem) st[mi][ni][r] = -1e30f;               \
    }                                                                             \
    /* ---- online softmax: interleaved shfl chains for both mi ---- */           \
    float mx[2];                                                                  \
    _Pragma("unroll")                                                             \
    for (int mi = 0; mi < 2; ++mi)                                                \
      mx[mi] = fmaxf(                                                             \
          fmaxf(fmaxf(fmaxf(st[mi][0][0], st[mi][0][1]), fmaxf(st[mi][0][2], st[mi][0][3])), \
                fmaxf(fmaxf(st[mi][1][0], st[mi][1][1]), fmaxf(st[mi][1][2], st[mi][1][3]))), \
          fmaxf(fmaxf(fmaxf(st[mi][2][0], st[mi][2][1]), fmaxf(st[mi][2][2], st[mi][2][3])), \
                fmaxf(fmaxf(st[mi][3][0], st[mi][3][1]), fmaxf(st[mi][3][2], st[mi][3][3])))); \
    _Pragma("unroll")                                                             \
    for (int mi = 0; mi < 2; ++mi) mx[mi] = fmaxf(mx[mi], __shfl_xor(mx[mi], 16));\
    _Pragma("unroll")                                                             \
    for (int mi = 0; mi < 2; ++mi) mx[mi] = fmaxf(mx[mi], __shfl_xor(mx[mi], 32));\
    _Pragma("unroll")                                                             \
    for (int mi = 0; mi < 2; ++mi) {                                              \
      if (!__all(mx[mi] - m2run[mi] <= THRRAW)) {                                 \
        const float mnew = fmaxf(m2run[mi], mx[mi]);                              \
        const float alpha = fast_exp2((m2run[mi] - mnew) * SCALE2);               \
        m2run[mi] = mnew;                                                         \
        lrun[mi] *= alpha;                                                        \
        _Pragma("unroll")                                                         \
        for (int nd = 0; nd < 4; ++nd)                                            \
          _Pragma("unroll")                                                       \
          for (int r = 0; r < 4; ++r) oacc[mi][nd][r] *= alpha;                   \
      }                                                                           \
    }                                                                             \
    float rs[2];                                                                  \
    _Pragma("unroll")                                                             \
    for (int mi = 0; mi < 2; ++mi) {                                              \
      const float msc = m2run[mi] * SCALE2;                                       \
      float a = 0.f;                                                              \
      const int qrow = mi * 16 + c;                                               \
      char* pbase = (char*)lP + qrow * 128;                                       \
      const int swz = (qrow & 7) << 4;                                            \
      _Pragma("unroll")                                                           \
      for (int ni = 0; ni < 4; ++ni) {                                            \
        float p0 = fast_exp2(fmaf(st[mi][ni][0], SCALE2, -msc));                  \
        float p1 = fast_exp2(fmaf(st[mi][ni][1], SCALE2, -msc));                  \
        float p2 = fast_exp2(fmaf(st[mi][ni][2], SCALE2, -msc));                  \
        float p3 = fast_exp2(fmaf(st[mi][ni][3], SCALE2, -msc));                  \
        a += (p0 + p1) + (p2 + p3);                                               \
        *(uint2*)(pbase + ((ni * 32 + g * 8) ^ swz)) =                            \
            make_uint2(cvtpk(p0, p1), cvtpk(p2, p3));                             \
      }                                                                           \
      rs[mi] = a;                                                                 \
    }                                                                             \
    _Pragma("unroll")                                                             \
    for (int mi = 0; mi < 2; ++mi) rs[mi] += __shfl_xor(rs[mi], 16);              \
    _Pragma("unroll")                                                             \
    for (int mi = 0; mi < 2; ++mi) rs[mi] += __shfl_xor(rs[mi], 32);              \
    _Pragma("unroll")                                                             \
    for (int mi = 0; mi < 2; ++mi) lrun[mi] += rs[mi];                            \
    /* ---- write V^T (packed key-pairs) into this wave's LDS ---- */             \
    _Pragma("unroll")                                                             \
    for (int dbb = 0; dbb < 4; ++dbb) {                                           \
      union { uint4 q; u16 s[8]; } u0, u1;                                        \
      u0.q = vv[dbb]; u1.q = vv[4 + dbb];                                         \
      const int dd0 = (dgr + dbb) * 8;                                            \
      _Pragma("unroll")                                                           \
      for (int j = 0; j < 8; ++j) {                                               \
        int d = dd0 + j;                                                          \
        *(unsigned*)((char*)lV + d * 128 + ((kp * 4) ^ ((d & 7) << 4))) =         \
            (unsigned)u0.s[j] | ((unsigned)u1.s[j] << 16);                        \
      }                                                                           \
    }                                                                             \
    /* ---- O^T += V^T P^T ---- */                                                \
    _Pragma("unroll")                                                             \
    for (int kb = 0; kb < 2; ++kb) {                                              \
      short8 pb[2], vf[4];                                                        \
      _Pragma("unroll")                                                           \
      for (int mi = 0; mi < 2; ++mi) {                                            \
        int qrow = mi * 16 + c;                                                   \
        pb[mi] = *(const short8*)((char*)lP + qrow * 128 +                        \
                                  ((kb * 64 + g * 16) ^ ((qrow & 7) << 4)));      \
      }                                                                           \
      _Pragma("unroll")                                                           \
      for (int nd = 0; nd < 4; ++nd) {                                            \
        int d = nd * 16 + c;                                                      \
        vf[nd] = *(const short8*)((char*)lV + d * 128 +                           \
                                  (((kb * 4 + g) ^ (d & 7)) << 4));               \
      }                                                                           \
      __builtin_amdgcn_s_setprio(1);                                              \
      _Pragma("unroll")                                                           \
      for (int mi = 0; mi < 2; ++mi)                                              \
        _Pragma("unroll")                                                         \
        for (int nd = 0; nd < 4; ++nd)                                            \
          oacc[mi][nd] = __builtin_amdgcn_mfma_f32_16x16x32_bf16(vf[nd], pb[mi], oacc[mi][nd], 0, 0, 0); \
      __builtin_amdgcn_s_setprio(0);                                              \
    }                                                                             \
  }

  LOADK(kS0, tA);
  int kt = tA;
  while (true) {
    if (kt + 1 < tB) LOADK(kS1, kt + 1);
    FLASH_BODY(kS0, kt)
    if (++kt >= tB) break;
    if (kt + 1 < tB) LOADK(kS0, kt + 1);
    FLASH_BODY(kS1, kt)
    if (++kt >= tB) break;
  }
#undef FLASH_BODY
#undef LOADK

  // ---- store partials: O^T lane (g,c): q=mi*16+c, d=nd*16+g*4+r; m stored base-2 ----
  const size_t pobase = ((size_t)(sp * 2 + b) * NHEAD + h) * NTOK;
#pragma unroll
  for (int mi = 0; mi < 2; ++mi) {
    const int pos = qt * 32 + mi * 16 + c;
    if (pos < cnt) {
      u16* op = partO + (pobase + pos) * 64;
#pragma unroll
      for (int nd = 0; nd < 4; ++nd) {
        ushort4 pk4;
        pk4.x = f2bf(oacc[mi][nd][0]);
        pk4.y = f2bf(oacc[mi][nd][1]);
        pk4.z = f2bf(oacc[mi][nd][2]);
        pk4.w = f2bf(oacc[mi][nd][3]);
        *(ushort4*)(op + nd * 16 + g * 4) = pk4;
      }
      if (g == 0)
        partML[pobase + pos] = make_float2(m2run[mi] * SCALE2, lrun[mi]);
    }
  }
}

// ---------------- merge split partials -> compact obf (bf16) ----------------
__global__ __launch_bounds__(256) void flash_merge_kernel(
    const u16* __restrict__ partO, const float2* __restrict__ partML,
    const int* __restrict__ cntE, u16* __restrict__ obf)
{
  const int bh = blockIdx.y;
  const int b = bh / NHEAD, h = bh % NHEAD;
  const int t = threadIdx.x;
  const int pos = blockIdx.x * 4 + (t >> 6);
  const int d = t & 63;
  const int cnt = cntE[b];
  if (pos >= cnt) return;
  const int ntiles = (cnt + 63) >> 6;
  const int per = (ntiles + NSPLIT - 1) / NSPLIT;

  float2 ml[NSPLIT];
  float M = -3e38f;
#pragma unroll
  for (int sp = 0; sp < NSPLIT; ++sp) {
    if (sp * per < ntiles) {
      ml[sp] = partML[((size_t)(sp * 2 + b) * NHEAD + h) * NTOK + pos];
      M = fmaxf(M, ml[sp].x);
    }
  }
  float L = 0.f, O = 0.f;
#pragma unroll
  for (int sp = 0; sp < NSPLIT; ++sp) {
    if (sp * per < ntiles) {
      const float e = fast_exp2(ml[sp].x - M);
      L += ml[sp].y * e;
      O += e * bf2f(partO[(((size_t)(sp * 2 + b) * NHEAD + h) * NTOK + pos) * 64 + d]);
    }
  }
  obf[((size_t)b * NTOK + pos) * CDIM + h * 64 + d] = f2bf(O / L);
}

// ---------------- masked mean pool partials ----------------
__global__ __launch_bounds__(256) void pool_partial_kernel(
    const float* __restrict__ h2, const int* __restrict__ edge, float* __restrict__ pooled)
{
  const int bid = blockIdx.x;                 // 96 = b*48 + cg*16 + ts
  const int b = bid / 48, rm = bid % 48;
  const int cg = rm / 16, ts = rm % 16;
  const int ch = cg * 256 + threadIdx.x;
  float s = 0.f;
  for (int tok = ts * 256; tok < ts * 256 + 256; ++tok) {
    if (!edge[b * NTOK + tok])
      s += h2[((size_t)b * NTOK + tok) * CDIM + ch];
  }
  atomicAdd(&pooled[b * CDIM + ch], s);
}

// ---------------- ECA conv(5) + sigmoid ----------------
__global__ void eca_kernel(const float* __restrict__ pooled, const float* __restrict__ w5,
                           const int* __restrict__ ecnt, float* __restrict__ gate)
{
  const int b = blockIdx.x, c = threadIdx.x;
  const float inv = 1.f / fmaxf((float)ecnt[b], 1.f);
  float a = 0.f;
#pragma unroll
  for (int j = 0; j < 5; ++j) {
    int i = c - 2 + j;
    if (i >= 0 && i < CDIM) a += w5[j] * pooled[b * CDIM + i];
  }
  a *= inv;
  gate[b * CDIM + c] = 1.f / (1.f + __expf(-a));
}

// ---------------- final scatter-combine ----------------
__global__ __launch_bounds__(256) void combine_kernel(
    const float* __restrict__ x, const float* __restrict__ attn,
    const float* __restrict__ h2, const float* __restrict__ gate,
    const int* __restrict__ edge, float* __restrict__ out)
{
  const size_t i = ((size_t)blockIdx.x * 256 + threadIdx.x) * 4;
  const int b = (int)(i / ((size_t)NTOK * CDIM));
  const size_t r = i % ((size_t)NTOK * CDIM);
  const int tok = (int)(r / CDIM);
  const int cc = (int)(r % CDIM);
  float4 ov;
  if (edge[b * NTOK + tok]) {
    ov = *(const float4*)(attn + i);
  } else {
    float4 xv = *(const float4*)(x + i);
    float4 hv = *(const float4*)(h2 + i);
    float4 gv = *(const float4*)(gate + b * CDIM + cc);
    ov.x = xv.x + hv.x * gv.x;
    ov.y = xv.y + hv.y * gv.y;
    ov.z = xv.z + hv.z * gv.z;
    ov.w = xv.w + hv.w * gv.w;
  }
  *(float4*)(out + i) = ov;
}

extern "C" void kernel_launch(void* const* d_in, const int* in_sizes, int n_in,
                              void* d_out, int out_size, void* d_ws, size_t ws_size,
                              hipStream_t stream) {
  const float* x      = (const float*)d_in[0];
  const float* ah     = (const float*)d_in[1];
  const float* qkv_w  = (const float*)d_in[2];
  const float* qkv_b  = (const float*)d_in[3];
  const float* proj_w = (const float*)d_in[4];
  const float* proj_b = (const float*)d_in[5];
  const float* ln_g   = (const float*)d_in[6];
  const float* ln_b   = (const float*)d_in[7];
  const float* fc1_w  = (const float*)d_in[8];
  const float* fc1_b  = (const float*)d_in[9];
  const float* fc2_w  = (const float*)d_in[10];
  const float* fc2_b  = (const float*)d_in[11];
  const float* eca_w  = (const float*)d_in[12];
  float* out = (float*)d_out;

  char* ws = (char*)d_ws;
  size_t off = 0;
  auto alloc = [&](size_t bytes) {
    char* p = ws + off;
    off += (bytes + 255) & ~(size_t)255;
    return p;
  };
  float* hint   = (float*)alloc((size_t)2 * NTOK * 4);
  int*   edge   = (int*)alloc((size_t)2 * NTOK * 4);
  int*   qidx   = (int*)alloc((size_t)2 * NTOK * 4);
  int*   eidx   = (int*)alloc((size_t)2 * NTOK * 4);
  int*   cntE   = (int*)alloc(256);
  int*   cntZ   = (int*)alloc(256);
  u16*   xbf    = (u16*)alloc((size_t)2 * NTOK * CDIM * 2);
  u16*   lnbf   = (u16*)alloc((size_t)2 * NTOK * CDIM * 2);
  u16*   qkvT   = (u16*)alloc((size_t)QKVD * CDIM * 2);
  u16*   projT  = (u16*)alloc((size_t)CDIM * CDIM * 2);
  u16*   fc1T   = (u16*)alloc((size_t)1536 * CDIM * 2);
  u16*   fc2T   = (u16*)alloc((size_t)CDIM * 1536 * 2);
  u16*   qkvb   = (u16*)alloc((size_t)2 * NTOK * QKVD * 2);
  u16*   obf    = (u16*)alloc((size_t)2 * NTOK * CDIM * 2);
  u16*   h1bf   = (u16*)alloc((size_t)2 * NTOK * 1536 * 2);   // 25.17 MB
  float* h2     = (float*)alloc((size_t)2 * NTOK * CDIM * 4); // 25.17 MB (contiguous after h1bf)
  float* attn   = (float*)alloc((size_t)2 * NTOK * CDIM * 4);
  float* pooled = (float*)alloc((size_t)2 * CDIM * 4);
  float* gate   = (float*)alloc((size_t)2 * CDIM * 4);
  // Aliased scratch (lifetimes disjoint, stream-ordered):
  //  partO (50.33 MB) over h1bf+h2: dead before fc1 writes h1bf.
  //  partML (3.15 MB) over attn: dead before proj writes attn.
  u16*   partO  = (u16*)h1bf;
  float* partML = attn;

  pool_hint_kernel<<<dim3(128), 256, 0, stream>>>(ah, hint);
  finalize_edge_kernel<<<dim3(2), 1024, 0, stream>>>(hint, edge, qidx, eidx, cntE, cntZ);
  ln_kernel<<<dim3(8192), 256, 0, stream>>>(x, ln_g, ln_b, lnbf, xbf);
  transpose_all_kernel<<<dim3(4608), 256, 0, stream>>>(
      qkv_w, proj_w, fc1_w, fc2_w, qkvT, projT, fc1T, fc2T);

  // qkv: gather edge rows -> compact qkvb
  gemm_bt<0, true, false, 128><<<dim3(64, 18), 256, 0, stream>>>(
      xbf, qkvT, qkv_b, nullptr, qidx, qkvb, 2304, 768);
  // flash over compact rows: barrier-free 1-wave blocks, split-K partials + merge
  flash_part_kernel<<<dim3(128, 24, NSPLIT), 64, 0, stream>>>(qkvb, cntE, partO, (float2*)partML);
  flash_merge_kernel<<<dim3(1024, 24), 256, 0, stream>>>(partO, (const float2*)partML, cntE, obf);
  // proj: direct compact A, scatter to full attn (+resid x)  [BN=64: 384 active blocks]
  gemm_bt<1, false, true, 64><<<dim3(64, 12), 256, 0, stream>>>(
      obf, projT, proj_b, x, qidx, attn, 768, 768);
  // fc1: gather easy rows -> compact h1
  gemm_bt<2, true, false, 128><<<dim3(64, 12), 256, 0, stream>>>(
      lnbf, fc1T, fc1_b, nullptr, eidx, h1bf, 1536, 768);
  // fc2: direct compact A, scatter to full h2  [BN=64: 384 active blocks]
  gemm_bt<3, false, true, 64><<<dim3(64, 12), 256, 0, stream>>>(
      h1bf, fc2T, fc2_b, nullptr, eidx, h2, 768, 1536);

  hipMemsetAsync(pooled, 0, (size_t)2 * CDIM * 4, stream);
  pool_partial_kernel<<<dim3(96), 256, 0, stream>>>(h2, edge, pooled);
  eca_kernel<<<dim3(2), 768, 0, stream>>>(pooled, eca_w, cntZ, gate);
  combine_kernel<<<dim3(6144), 256, 0, stream>>>(x, attn, h2, gate, edge, out);
}

// Round 10
// 458.480 us; speedup vs baseline: 1.2069x; 1.0073x over previous
//
#include <hip/hip_runtime.h>

using u16 = unsigned short;
using short8 = __attribute__((ext_vector_type(8))) short;
using f32x4 = __attribute__((ext_vector_type(4))) float;

#define NTOK 4096
#define CDIM 768
#define QKVD 2304
#define NHEAD 12
#define NSPLIT 4
// elements per head-major sector: 2 batches * 12 heads * 4096 tok * 64 d
#define QHSZ_ELEM ((size_t)2 * 12 * 4096 * 64)
// 0.125 (1/sqrt(64)) * log2(e)
#define SCALE2 0.18033688011112042f
// defer-max threshold: 8 (base-2) in raw-score units = 8/SCALE2
#define THRRAW 44.3614195558f

__device__ __forceinline__ u16 f2bf(float f) {
  unsigned u = __float_as_uint(f);
  u += 0x7FFFu + ((u >> 16) & 1u);
  return (u16)(u >> 16);
}
__device__ __forceinline__ float bf2f(u16 v) {
  return __uint_as_float(((unsigned)v) << 16);
}
__device__ __forceinline__ float fast_exp2(float x) {
  float r;
  asm("v_exp_f32 %0, %1" : "=v"(r) : "v"(x));
  return r;
}
__device__ __forceinline__ unsigned cvtpk(float lo, float hi) {
  unsigned r;
  asm("v_cvt_pk_bf16_f32 %0, %1, %2" : "=v"(r) : "v"(lo), "v"(hi));
  return r;
}

__device__ __forceinline__ void gload_lds16(const void* g, void* l) {
  __builtin_amdgcn_global_load_lds(
      (__attribute__((address_space(1))) void*)g,
      (__attribute__((address_space(3))) void*)l, 16u, 0, 0u);
}

__device__ __forceinline__ float gelu_exact(float z) {
  return 0.5f * z * (1.0f + erff(z * 0.70710678118654752f));
}

// ---------------- edge mask: pool 16x16 blocks of alpha_hint ----------------
__global__ __launch_bounds__(256) void pool_hint_kernel(
    const float* __restrict__ ah, float* __restrict__ hint)
{
  const int bid = blockIdx.x;            // B*64 blocks: (b, cellrow)
  const int b = bid >> 6, cr = bid & 63;
  const int t = threadIdx.x;
  const float* base = ah + ((size_t)b * 1024 + (size_t)cr * 16) * 1024;
  float s = 0.f;
#pragma unroll
  for (int pr = 0; pr < 16; ++pr) {
    float4 v = *(const float4*)(base + (size_t)pr * 1024 + t * 4);
    s += v.x + v.y + v.z + v.w;
  }
  s += __shfl_xor(s, 1);
  s += __shfl_xor(s, 2);
  if ((t & 3) == 0)
    hint[b * NTOK + cr * 64 + (t >> 2)] = s * (1.f / 256.f);
}

__global__ __launch_bounds__(1024) void finalize_edge_kernel(
    const float* __restrict__ hint, int* __restrict__ edge,
    int* __restrict__ qidx, int* __restrict__ eidx,
    int* __restrict__ cntE, int* __restrict__ cntZ)
{
  const int b = blockIdx.x, t = threadIdx.x;
  __shared__ int wsum[16];
  __shared__ int scntE, scntZ, stot;
  int bits[4]; int s = 0;
#pragma unroll
  for (int j = 0; j < 4; ++j) {
    float h = hint[b * NTOK + t * 4 + j];
    bits[j] = (h > 0.02f && h < 0.98f) ? 1 : 0;
    s += bits[j];
    qidx[b * NTOK + t * 4 + j] = -1;
    eidx[b * NTOK + t * 4 + j] = -1;
  }
  int sw = s;
#pragma unroll
  for (int d = 1; d < 64; d <<= 1) sw += __shfl_xor(sw, d);
  const int l = t & 63, w = t >> 6;
  if (l == 0) wsum[w] = sw;
  if (t == 0) { scntE = 0; scntZ = 0; }
  __syncthreads();
  if (t == 0) { int a = 0; for (int i = 0; i < 16; ++i) a += wsum[i]; stot = a; }
  __syncthreads();
  const bool fb = stot < 64;     // fallback: route everything to attention
#pragma unroll
  for (int j = 0; j < 4; ++j) {
    int e = fb ? 1 : bits[j];
    edge[b * NTOK + t * 4 + j] = e;
    if (e) {
      int p = atomicAdd(&scntE, 1);
      qidx[b * NTOK + p] = t * 4 + j;
    } else {
      int p = atomicAdd(&scntZ, 1);
      eidx[b * NTOK + p] = t * 4 + j;
    }
  }
  __syncthreads();
  if (t == 0) { cntE[b] = scntE; cntZ[b] = scntZ; }
}

// ---------------- LayerNorm (writes ln bf16) + x->bf16 ----------------
__global__ __launch_bounds__(256) void ln_kernel(
    const float* __restrict__ x, const float* __restrict__ gam,
    const float* __restrict__ bet, u16* __restrict__ lnb, u16* __restrict__ xb)
{
  const int row = blockIdx.x, t = threadIdx.x;
  const float* xr = x + (size_t)row * CDIM;
  float v[3];
#pragma unroll
  for (int j = 0; j < 3; ++j) v[j] = xr[t + j * 256];
  float s = v[0] + v[1] + v[2];
  float ss = v[0] * v[0] + v[1] * v[1] + v[2] * v[2];
#pragma unroll
  for (int d = 1; d < 64; d <<= 1) { s += __shfl_xor(s, d); ss += __shfl_xor(ss, d); }
  __shared__ float red[8];
  const int l = t & 63, w = t >> 6;
  if (l == 0) { red[w * 2] = s; red[w * 2 + 1] = ss; }
  __syncthreads();
  s = red[0] + red[2] + red[4] + red[6];
  ss = red[1] + red[3] + red[5] + red[7];
  const float mu = s * (1.f / 768.f);
  const float rstd = rsqrtf(ss * (1.f / 768.f) - mu * mu + 1e-5f);
#pragma unroll
  for (int j = 0; j < 3; ++j) {
    const int cc = t + j * 256;
    lnb[(size_t)row * CDIM + cc] = f2bf((v[j] - mu) * rstd * gam[cc] + bet[cc]);
    xb[(size_t)row * CDIM + cc] = f2bf(v[j]);
  }
}

// ---------------- fused fp32 [K,N] -> bf16 [N,K] transposes (4 weights) ----------------
__global__ __launch_bounds__(256) void transpose_all_kernel(
    const float* __restrict__ qkv_w, const float* __restrict__ proj_w,
    const float* __restrict__ fc1_w, const float* __restrict__ fc2_w,
    u16* __restrict__ qkvT, u16* __restrict__ projT,
    u16* __restrict__ fc1T, u16* __restrict__ fc2T)
{
  __shared__ float tile[32][33];
  int bid = blockIdx.x;
  const float* in; u16* outp; int K, N, bx, by;
  if (bid < 1728)      { in = qkv_w;  outp = qkvT; K = 768;  N = 2304; bx = bid % 72; by = bid / 72; }
  else if (bid < 2304) { bid -= 1728; in = proj_w; outp = projT; K = 768;  N = 768;  bx = bid % 24; by = bid / 24; }
  else if (bid < 3456) { bid -= 2304; in = fc1_w;  outp = fc1T; K = 768;  N = 1536; bx = bid % 48; by = bid / 48; }
  else                 { bid -= 3456; in = fc2_w;  outp = fc2T; K = 1536; N = 768;  bx = bid % 24; by = bid / 24; }
  const int tx = threadIdx.x & 31, ty = threadIdx.x >> 5;
#pragma unroll
  for (int j = 0; j < 32; j += 8)
    tile[ty + j][tx] = in[(size_t)(by * 32 + ty + j) * N + bx * 32 + tx];
  __syncthreads();
#pragma unroll
  for (int j = 0; j < 32; j += 8)
    outp[(size_t)(bx * 32 + ty + j) * K + by * 32 + tx] = f2bf(tile[tx][ty + j]);
}

// ---------------- bf16 MFMA GEMM with optional row gather/scatter ----------------
// EPI: 0 = +bias -> bf16 (compact out); 1 = +bias+resid -> f32 (scatter out);
//      2 = gelu(gelu(+bias)) -> bf16 (compact out); 3 = +bias -> f32 (scatter out)
//      4 = +bias -> bf16 head-major QKV split (compact rows)
// BN: 128 (wave = 64x64, 4x4 frags) or 64 (wave = 64x32, 4x2 frags)
template <int EPI, bool GATHER_A, bool SCATTER_OUT, int BN>
__global__ __launch_bounds__(256) void gemm_bt(
    const u16* __restrict__ A, const u16* __restrict__ Bt,
    const float* __restrict__ bias, const float* __restrict__ resid,
    const int* __restrict__ list, void* __restrict__ outp, int N, int K)
{
  constexpr int NN = BN / 32;                       // N-frags per wave
  const int bm = blockIdx.x, bn = blockIdx.y;
  const int b = bm >> 5, bmi = bm & 31;
  const int rb = bmi * 128;                         // position base within batch
  if (list[b * NTOK + rb] < 0) return;              // whole block beyond count

  __shared__ __align__(16) u16 lA[128 * 32];
  __shared__ __align__(16) u16 lB[BN * 32];
  const int t = threadIdx.x;
  const int l = t & 63, w = t >> 6;
  const int g = l >> 4, c = l & 15;
  const int wr = w >> 1, wc = w & 1;

  f32x4 acc[4][NN];
#pragma unroll
  for (int i = 0; i < 4; ++i)
#pragma unroll
    for (int j = 0; j < NN; ++j) acc[i][j] = f32x4{0.f, 0.f, 0.f, 0.f};

  const int srow = t >> 2;                      // 0..63
  const int sslot = (t & 3) ^ (srow & 3);       // pre-swizzled source slot
  int ta0, ta1;
  if constexpr (GATHER_A) {
    ta0 = list[b * NTOK + rb + srow];       if (ta0 < 0) ta0 = 0;
    ta1 = list[b * NTOK + rb + 64 + srow];  if (ta1 < 0) ta1 = 0;
  } else {
    ta0 = rb + srow;
    ta1 = rb + 64 + srow;
  }
  const u16* gA0 = A + ((size_t)b * NTOK + ta0) * K + sslot * 8;
  const u16* gA1 = A + ((size_t)b * NTOK + ta1) * K + sslot * 8;
  const u16* gB0 = Bt + (size_t)(bn * BN + srow) * K + sslot * 8;
  const u16* gB1 = (BN == 128) ? Bt + (size_t)(bn * BN + 64 + srow) * K + sslot * 8 : nullptr;
  char* ldA = (char*)lA + w * 1024;
  char* ldB = (char*)lB + w * 1024;

  for (int k0 = 0; k0 < K; k0 += 32) {
    __syncthreads();
    gload_lds16(gA0 + k0, ldA);
    gload_lds16(gA1 + k0, ldA + 4096);
    gload_lds16(gB0 + k0, ldB);
    if constexpr (BN == 128) gload_lds16(gB1 + k0, ldB + 4096);
    __syncthreads();
    short8 af[4], bfr[NN];
#pragma unroll
    for (int mi = 0; mi < 4; ++mi) {
      int row = wr * 64 + mi * 16 + c;
      af[mi] = *(const short8*)((const char*)lA + row * 64 + ((g ^ (row & 3)) << 4));
    }
#pragma unroll
    for (int ni = 0; ni < NN; ++ni) {
      int row = wc * (BN / 2) + ni * 16 + c;
      bfr[ni] = *(const short8*)((const char*)lB + row * 64 + ((g ^ (row & 3)) << 4));
    }
#pragma unroll
    for (int mi = 0; mi < 4; ++mi)
#pragma unroll
      for (int ni = 0; ni < NN; ++ni)
        acc[mi][ni] = __builtin_amdgcn_mfma_f32_16x16x32_bf16(af[mi], bfr[ni], acc[mi][ni], 0, 0, 0);
  }

#pragma unroll
  for (int mi = 0; mi < 4; ++mi) {
#pragma unroll
    for (int ni = 0; ni < NN; ++ni) {
      const int col = bn * BN + wc * (BN / 2) + ni * 16 + c;
      const float bv = bias[col];
      const int prow0 = rb + wr * 64 + mi * 16 + g * 4;
#pragma unroll
      for (int r = 0; r < 4; ++r) {
        float v = acc[mi][ni][r] + bv;
        int orow;
        if constexpr (SCATTER_OUT) {
          int tok = list[b * NTOK + prow0 + r];
          if (tok < 0) continue;
          orow = tok;
        } else {
          orow = prow0 + r;
        }
        if constexpr (EPI == 4) {
          // head-major split: sector 0=Q,1=K,2=V ; [sector][(b*12+h)][tok][64]
          const int h_all = col >> 6;                // 0..35
          const int sec = (h_all >= 24) ? 2 : (h_all >= 12 ? 1 : 0);
          const int hh = h_all - sec * 12;
          ((u16*)outp)[(size_t)sec * QHSZ_ELEM +
                       (((size_t)(b * 12 + hh) * NTOK + orow) << 6) + (col & 63)] = f2bf(v);
        } else {
          const size_t idx = ((size_t)b * NTOK + orow) * N + col;
          if constexpr (EPI == 0) {
            ((u16*)outp)[idx] = f2bf(v);
          } else if constexpr (EPI == 1) {
            ((float*)outp)[idx] = v + resid[idx];
          } else if constexpr (EPI == 2) {
            ((u16*)outp)[idx] = f2bf(gelu_exact(gelu_exact(v)));
          } else if constexpr (EPI == 3) {
            ((float*)outp)[idx] = v;
          }
        }
      }
    }
  }
}

// ---------------- flash attention partials: barrier-free, head-major QKV ----------------
// grid (24 bh, 128 qblocks of 32, NSPLIT): bh fastest so bh -> XCD is stable (24%8==0)
// and each XCD's L2 holds only its 3 bh's K/V (dense 8KB tiles, fully coalesced).
__global__ __launch_bounds__(64) void flash_part_kernel(
    const u16* __restrict__ qkvh, const int* __restrict__ cntE,
    u16* __restrict__ partO, float2* __restrict__ partML)
{
  const int bh = blockIdx.x;
  const int qt = blockIdx.y;
  const int sp = blockIdx.z;
  const int b = bh / NHEAD, h = bh % NHEAD;
  const int cnt = cntE[b];
  if (qt * 32 >= cnt) return;

  const int ntiles = (cnt + 63) >> 6;
  const int per = (ntiles + NSPLIT - 1) / NSPLIT;
  const int tA = sp * per;
  const int tB = min(ntiles, tA + per);
  if (tA >= tB) return;

  __shared__ __align__(16) u16 lV[64 * 64];      // this wave's V^T, swizzled (8KB)
  __shared__ __align__(16) u16 lP[32 * 64];      // this wave's P^T bounce (4KB)

  const int l = threadIdx.x;
  const int g = l >> 4, c = l & 15;
  const int kp = l & 31, dgr = (l >> 5) * 4;     // V staging: key-pair, d-block group
  const size_t bhbase = (size_t)bh * NTOK * 64;
  const u16* Qh = qkvh + bhbase;
  const u16* Kh = qkvh + QHSZ_ELEM + bhbase;
  const u16* Vh = qkvh + 2 * QHSZ_ELEM + bhbase;

  // Q fragments (B-operand): lane holds q = qt*32 + mi*16 + c, d-slice kb*32+g*8
  short8 qf[2][2];
#pragma unroll
  for (int mi = 0; mi < 2; ++mi) {
    const u16* qp = Qh + ((size_t)(qt * 32 + mi * 16 + c) << 6);
#pragma unroll
    for (int kb = 0; kb < 2; ++kb)
      qf[mi][kb] = *(const short8*)(qp + kb * 32 + g * 8);
  }

  f32x4 oacc[2][4];            // O^T: [mi(q)][nd(d)]: lane (g,c): d=nd*16+g*4+r, q=mi*16+c
  float m2run[2], lrun[2];     // m2run in RAW score units
#pragma unroll
  for (int mi = 0; mi < 2; ++mi) {
#pragma unroll
    for (int nd = 0; nd < 4; ++nd) oacc[mi][nd] = f32x4{0.f, 0.f, 0.f, 0.f};
    m2run[mi] = -1e30f; lrun[mi] = 0.f;
  }

  // K fragment register sets (A-operand): lane (c,g): K[key=ni*16+c][d=kb*32+g*8..+8]
  short8 kS0[4][2], kS1[4][2];

#define LOADK(KS, kt)                                                             \
  {                                                                               \
    const u16* kg = Kh + ((size_t)((kt) * 64 + c) << 6) + g * 8;                  \
    _Pragma("unroll")                                                             \
    for (int ni = 0; ni < 4; ++ni)                                                \
      _Pragma("unroll")                                                           \
      for (int kb = 0; kb < 2; ++kb)                                              \
        KS[ni][kb] = *(const short8*)(kg + ni * 1024 + kb * 32);                  \
  }

#define FLASH_BODY(KS, kt)                                                        \
  {                                                                               \
    const bool msk = ((kt) * 64 + 64 > cnt);                                      \
    const int rem = cnt - (kt) * 64;                                              \
    /* V loads for this tile (dense; latency hidden under QK + softmax) */        \
    uint4 vv[8];                                                                  \
    {                                                                             \
      const u16* vg = Vh + ((size_t)((kt) * 64 + kp * 2) << 6) + dgr * 8;         \
      _Pragma("unroll")                                                           \
      for (int dbb = 0; dbb < 4; ++dbb) {                                         \
        vv[dbb]     = *(const uint4*)(vg + dbb * 8);                              \
        vv[4 + dbb] = *(const uint4*)(vg + 64 + dbb * 8);                         \
      }                                                                           \
    }                                                                             \
    /* ---- S^T = K Q^T ---- */                                                   \
    f32x4 st[2][4];                                                               \
    __builtin_amdgcn_s_setprio(1);                                                \
    _Pragma("unroll")                                                             \
    for (int mi = 0; mi < 2; ++mi)                                                \
      _Pragma("unroll")                                                           \
      for (int ni = 0; ni < 4; ++ni) {                                            \
        f32x4 sv = f32x4{0.f, 0.f, 0.f, 0.f};                                     \
        sv = __builtin_amdgcn_mfma_f32_16x16x32_bf16(KS[ni][0], qf[mi][0], sv, 0, 0, 0); \
        sv = __builtin_amdgcn_mfma_f32_16x16x32_bf16(KS[ni][1], qf[mi][1], sv, 0, 0, 0); \
        st[mi][ni] = sv;                                                          \
      }                                                                           \
    __builtin_amdgcn_s_setprio(0);                                                \
    if (msk) {                                                                    \
      _Pragma("unroll")                                                           \
      for (int mi = 0; mi < 2; ++mi)                                              \
        _Pragma("unroll")                                                         \
        for (int ni = 0; ni < 4; ++ni)                                            \
          _Pragma("unroll")                                                       \
          for (int r = 0; r < 4; ++r)                                             \
            if (ni * 16 + g * 4 + r >= rem) st[mi][ni][r] = -1e30f;               \
    }                                                                             \
    /* ---- online softmax: interleaved shfl chains for both mi ---- */           \
    float mx[2];                                                                  \
    _Pragma("unroll")                                                             \
    for (int mi = 0; mi < 2; ++mi)                                                \
      mx[mi] = fmaxf(                                                             \
          fmaxf(fmaxf(fmaxf(st[mi][0][0], st[mi][0][1]), fmaxf(st[mi][0][2], st[mi][0][3])), \
                fmaxf(fmaxf(st[mi][1][0], st[mi][1][1]), fmaxf(st[mi][1][2], st[mi][1][3]))), \
          fmaxf(fmaxf(fmaxf(st[mi][2][0], st[mi][2][1]), fmaxf(st[mi][2][2], st[mi][2][3])), \
                fmaxf(fmaxf(st[mi][3][0], st[mi][3][1]), fmaxf(st[mi][3][2], st[mi][3][3])))); \
    _Pragma("unroll")                                                             \
    for (int mi = 0; mi < 2; ++mi) mx[mi] = fmaxf(mx[mi], __shfl_xor(mx[mi], 16));\
    _Pragma("unroll")                                                             \
    for (int mi = 0; mi < 2; ++mi) mx[mi] = fmaxf(mx[mi], __shfl_xor(mx[mi], 32));\
    _Pragma("unroll")                                                             \
    for (int mi = 0; mi < 2; ++mi) {                                              \
      if (!__all(mx[mi] - m2run[mi] <= THRRAW)) {                                 \
        const float mnew = fmaxf(m2run[mi], mx[mi]);                              \
        const float alpha = fast_exp2((m2run[mi] - mnew) * SCALE2);               \
        m2run[mi] = mnew;                                                         \
        lrun[mi] *= alpha;                                                        \
        _Pragma("unroll")                                                         \
        for (int nd = 0; nd < 4; ++nd)                                            \
          _Pragma("unroll")                                                       \
          for (int r = 0; r < 4; ++r) oacc[mi][nd][r] *= alpha;                   \
      }                                                                           \
    }                                                                             \
    float rs[2];                                                                  \
    _Pragma("unroll")                                                             \
    for (int mi = 0; mi < 2; ++mi) {                                              \
      const float msc = m2run[mi] * SCALE2;                                       \
      float a = 0.f;                                                              \
      const int qrow = mi * 16 + c;                                               \
      char* pbase = (char*)lP + qrow * 128;                                       \
      const int swz = (qrow & 7) << 4;                                            \
      _Pragma("unroll")                                                           \
      for (int ni = 0; ni < 4; ++ni) {                                            \
        float p0 = fast_exp2(fmaf(st[mi][ni][0], SCALE2, -msc));                  \
        float p1 = fast_exp2(fmaf(st[mi][ni][1], SCALE2, -msc));                  \
        float p2 = fast_exp2(fmaf(st[mi][ni][2], SCALE2, -msc));                  \
        float p3 = fast_exp2(fmaf(st[mi][ni][3], SCALE2, -msc));                  \
        a += (p0 + p1) + (p2 + p3);                                               \
        *(uint2*)(pbase + ((ni * 32 + g * 8) ^ swz)) =                            \
            make_uint2(cvtpk(p0, p1), cvtpk(p2, p3));                             \
      }                                                                           \
      rs[mi] = a;                                                                 \
    }                                                                             \
    _Pragma("unroll")                                                             \
    for (int mi = 0; mi < 2; ++mi) rs[mi] += __shfl_xor(rs[mi], 16);              \
    _Pragma("unroll")                                                             \
    for (int mi = 0; mi < 2; ++mi) rs[mi] += __shfl_xor(rs[mi], 32);              \
    _Pragma("unroll")                                                             \
    for (int mi = 0; mi < 2; ++mi) lrun[mi] += rs[mi];                            \
    /* ---- write V^T (packed key-pairs) into this wave's LDS ---- */             \
    _Pragma("unroll")                                                             \
    for (int dbb = 0; dbb < 4; ++dbb) {                                           \
      union { uint4 q; u16 s[8]; } u0, u1;                                        \
      u0.q = vv[dbb]; u1.q = vv[4 + dbb];                                         \
      const int dd0 = (dgr + dbb) * 8;                                            \
      _Pragma("unroll")                                                           \
      for (int j = 0; j < 8; ++j) {                                               \
        int d = dd0 + j;                                                          \
        *(unsigned*)((char*)lV + d * 128 + ((kp * 4) ^ ((d & 7) << 4))) =         \
            (unsigned)u0.s[j] | ((unsigned)u1.s[j] << 16);                        \
      }                                                                           \
    }                                                                             \
    /* ---- O^T += V^T P^T ---- */                                                \
    _Pragma("unroll")                                                             \
    for (int kb = 0; kb < 2; ++kb) {                                              \
      short8 pb[2], vf[4];                                                        \
      _Pragma("unroll")                                                           \
      for (int mi = 0; mi < 2; ++mi) {                                            \
        int qrow = mi * 16 + c;                                                   \
        pb[mi] = *(const short8*)((char*)lP + qrow * 128 +                        \
                                  ((kb * 64 + g * 16) ^ ((qrow & 7) << 4)));      \
      }                                                                           \
      _Pragma("unroll")                                                           \
      for (int nd = 0; nd < 4; ++nd) {                                            \
        int d = nd * 16 + c;                                                      \
        vf[nd] = *(const short8*)((char*)lV + d * 128 +                           \
                                  (((kb * 4 + g) ^ (d & 7)) << 4));               \
      }                                                                           \
      __builtin_amdgcn_s_setprio(1);                                              \
      _Pragma("unroll")                                                           \
      for (int mi = 0; mi < 2; ++mi)                                              \
        _Pragma("unroll")                                                         \
        for (int nd = 0; nd < 4; ++nd)                                            \
          oacc[mi][nd] = __builtin_amdgcn_mfma_f32_16x16x32_bf16(vf[nd], pb[mi], oacc[mi][nd], 0, 0, 0); \
      __builtin_amdgcn_s_setprio(0);                                              \
    }                                                                             \
  }

  LOADK(kS0, tA);
  int kt = tA;
  while (true) {
    if (kt + 1 < tB) LOADK(kS1, kt + 1);
    FLASH_BODY(kS0, kt)
    if (++kt >= tB) break;
    if (kt + 1 < tB) LOADK(kS0, kt + 1);
    FLASH_BODY(kS1, kt)
    if (++kt >= tB) break;
  }
#undef FLASH_BODY
#undef LOADK

  // ---- store partials: O^T lane (g,c): q=mi*16+c, d=nd*16+g*4+r; m stored base-2 ----
  const size_t pobase = ((size_t)(sp * 2 + b) * NHEAD + h) * NTOK;
#pragma unroll
  for (int mi = 0; mi < 2; ++mi) {
    const int pos = qt * 32 + mi * 16 + c;
    if (pos < cnt) {
      u16* op = partO + (pobase + pos) * 64;
#pragma unroll
      for (int nd = 0; nd < 4; ++nd) {
        ushort4 pk4;
        pk4.x = f2bf(oacc[mi][nd][0]);
        pk4.y = f2bf(oacc[mi][nd][1]);
        pk4.z = f2bf(oacc[mi][nd][2]);
        pk4.w = f2bf(oacc[mi][nd][3]);
        *(ushort4*)(op + nd * 16 + g * 4) = pk4;
      }
      if (g == 0)
        partML[pobase + pos] = make_float2(m2run[mi] * SCALE2, lrun[mi]);
    }
  }
}

// ---------------- merge split partials -> compact obf (bf16) ----------------
__global__ __launch_bounds__(256) void flash_merge_kernel(
    const u16* __restrict__ partO, const float2* __restrict__ partML,
    const int* __restrict__ cntE, u16* __restrict__ obf)
{
  const int bh = blockIdx.y;
  const int b = bh / NHEAD, h = bh % NHEAD;
  const int t = threadIdx.x;
  const int pos = blockIdx.x * 4 + (t >> 6);
  const int d = t & 63;
  const int cnt = cntE[b];
  if (pos >= cnt) return;
  const int ntiles = (cnt + 63) >> 6;
  const int per = (ntiles + NSPLIT - 1) / NSPLIT;

  float2 ml[NSPLIT];
  float M = -3e38f;
#pragma unroll
  for (int sp = 0; sp < NSPLIT; ++sp) {
    if (sp * per < ntiles) {
      ml[sp] = partML[((size_t)(sp * 2 + b) * NHEAD + h) * NTOK + pos];
      M = fmaxf(M, ml[sp].x);
    }
  }
  float L = 0.f, O = 0.f;
#pragma unroll
  for (int sp = 0; sp < NSPLIT; ++sp) {
    if (sp * per < ntiles) {
      const float e = fast_exp2(ml[sp].x - M);
      L += ml[sp].y * e;
      O += e * bf2f(partO[(((size_t)(sp * 2 + b) * NHEAD + h) * NTOK + pos) * 64 + d]);
    }
  }
  obf[((size_t)b * NTOK + pos) * CDIM + h * 64 + d] = f2bf(O / L);
}

// ---------------- masked mean pool partials ----------------
__global__ __launch_bounds__(256) void pool_partial_kernel(
    const float* __restrict__ h2, const int* __restrict__ edge, float* __restrict__ pooled)
{
  const int bid = blockIdx.x;                 // 96 = b*48 + cg*16 + ts
  const int b = bid / 48, rm = bid % 48;
  const int cg = rm / 16, ts = rm % 16;
  const int ch = cg * 256 + threadIdx.x;
  float s = 0.f;
  for (int tok = ts * 256; tok < ts * 256 + 256; ++tok) {
    if (!edge[b * NTOK + tok])
      s += h2[((size_t)b * NTOK + tok) * CDIM + ch];
  }
  atomicAdd(&pooled[b * CDIM + ch], s);
}

// ---------------- ECA conv(5) + sigmoid ----------------
__global__ void eca_kernel(const float* __restrict__ pooled, const float* __restrict__ w5,
                           const int* __restrict__ ecnt, float* __restrict__ gate)
{
  const int b = blockIdx.x, c = threadIdx.x;
  const float inv = 1.f / fmaxf((float)ecnt[b], 1.f);
  float a = 0.f;
#pragma unroll
  for (int j = 0; j < 5; ++j) {
    int i = c - 2 + j;
    if (i >= 0 && i < CDIM) a += w5[j] * pooled[b * CDIM + i];
  }
  a *= inv;
  gate[b * CDIM + c] = 1.f / (1.f + __expf(-a));
}

// ---------------- final scatter-combine ----------------
__global__ __launch_bounds__(256) void combine_kernel(
    const float* __restrict__ x, const float* __restrict__ attn,
    const float* __restrict__ h2, const float* __restrict__ gate,
    const int* __restrict__ edge, float* __restrict__ out)
{
  const size_t i = ((size_t)blockIdx.x * 256 + threadIdx.x) * 4;
  const int b = (int)(i / ((size_t)NTOK * CDIM));
  const size_t r = i % ((size_t)NTOK * CDIM);
  const int tok = (int)(r / CDIM);
  const int cc = (int)(r % CDIM);
  float4 ov;
  if (edge[b * NTOK + tok]) {
    ov = *(const float4*)(attn + i);
  } else {
    float4 xv = *(const float4*)(x + i);
    float4 hv = *(const float4*)(h2 + i);
    float4 gv = *(const float4*)(gate + b * CDIM + cc);
    ov.x = xv.x + hv.x * gv.x;
    ov.y = xv.y + hv.y * gv.y;
    ov.z = xv.z + hv.z * gv.z;
    ov.w = xv.w + hv.w * gv.w;
  }
  *(float4*)(out + i) = ov;
}

extern "C" void kernel_launch(void* const* d_in, const int* in_sizes, int n_in,
                              void* d_out, int out_size, void* d_ws, size_t ws_size,
                              hipStream_t stream) {
  const float* x      = (const float*)d_in[0];
  const float* ah     = (const float*)d_in[1];
  const float* qkv_w  = (const float*)d_in[2];
  const float* qkv_b  = (const float*)d_in[3];
  const float* proj_w = (const float*)d_in[4];
  const float* proj_b = (const float*)d_in[5];
  const float* ln_g   = (const float*)d_in[6];
  const float* ln_b   = (const float*)d_in[7];
  const float* fc1_w  = (const float*)d_in[8];
  const float* fc1_b  = (const float*)d_in[9];
  const float* fc2_w  = (const float*)d_in[10];
  const float* fc2_b  = (const float*)d_in[11];
  const float* eca_w  = (const float*)d_in[12];
  float* out = (float*)d_out;

  char* ws = (char*)d_ws;
  size_t off = 0;
  auto alloc = [&](size_t bytes) {
    char* p = ws + off;
    off += (bytes + 255) & ~(size_t)255;
    return p;
  };
  float* hint   = (float*)alloc((size_t)2 * NTOK * 4);
  int*   edge   = (int*)alloc((size_t)2 * NTOK * 4);
  int*   qidx   = (int*)alloc((size_t)2 * NTOK * 4);
  int*   eidx   = (int*)alloc((size_t)2 * NTOK * 4);
  int*   cntE   = (int*)alloc(256);
  int*   cntZ   = (int*)alloc(256);
  u16*   xbf    = (u16*)alloc((size_t)2 * NTOK * CDIM * 2);
  u16*   lnbf   = (u16*)alloc((size_t)2 * NTOK * CDIM * 2);
  u16*   qkvT   = (u16*)alloc((size_t)QKVD * CDIM * 2);
  u16*   projT  = (u16*)alloc((size_t)CDIM * CDIM * 2);
  u16*   fc1T   = (u16*)alloc((size_t)1536 * CDIM * 2);
  u16*   fc2T   = (u16*)alloc((size_t)CDIM * 1536 * 2);
  u16*   qkvh   = (u16*)alloc((size_t)3 * QHSZ_ELEM * 2);     // head-major Q,K,V
  u16*   obf    = (u16*)alloc((size_t)2 * NTOK * CDIM * 2);
  u16*   h1bf   = (u16*)alloc((size_t)2 * NTOK * 1536 * 2);   // 25.17 MB
  float* h2     = (float*)alloc((size_t)2 * NTOK * CDIM * 4); // 25.17 MB (contiguous after h1bf)
  float* attn   = (float*)alloc((size_t)2 * NTOK * CDIM * 4);
  float* pooled = (float*)alloc((size_t)2 * CDIM * 4);
  float* gate   = (float*)alloc((size_t)2 * CDIM * 4);
  // Aliased scratch (lifetimes disjoint, stream-ordered):
  //  partO (50.33 MB) over h1bf+h2: dead before fc1 writes h1bf.
  //  partML (3.15 MB) over attn: dead before proj writes attn.
  u16*   partO  = (u16*)h1bf;
  float* partML = attn;

  pool_hint_kernel<<<dim3(128), 256, 0, stream>>>(ah, hint);
  finalize_edge_kernel<<<dim3(2), 1024, 0, stream>>>(hint, edge, qidx, eidx, cntE, cntZ);
  ln_kernel<<<dim3(8192), 256, 0, stream>>>(x, ln_g, ln_b, lnbf, xbf);
  transpose_all_kernel<<<dim3(4608), 256, 0, stream>>>(
      qkv_w, proj_w, fc1_w, fc2_w, qkvT, projT, fc1T, fc2T);

  // qkv: gather edge rows -> compact head-major Qh/Kh/Vh
  gemm_bt<4, true, false, 128><<<dim3(64, 18), 256, 0, stream>>>(
      xbf, qkvT, qkv_b, nullptr, qidx, qkvh, 2304, 768);
  // flash over compact rows: barrier-free 1-wave blocks, dense head-major tiles
  flash_part_kernel<<<dim3(24, 128, NSPLIT), 64, 0, stream>>>(qkvh, cntE, partO, (float2*)partML);
  flash_merge_kernel<<<dim3(1024, 24), 256, 0, stream>>>(partO, (const float2*)partML, cntE, obf);
  // proj: direct compact A, scatter to full attn (+resid x)  [BN=64: 384 active blocks]
  gemm_bt<1, false, true, 64><<<dim3(64, 12), 256, 0, stream>>>(
      obf, projT, proj_b, x, qidx, attn, 768, 768);
  // fc1: gather easy rows -> compact h1
  gemm_bt<2, true, false, 128><<<dim3(64, 12), 256, 0, stream>>>(
      lnbf, fc1T, fc1_b, nullptr, eidx, h1bf, 1536, 768);
  // fc2: direct compact A, scatter to full h2  [BN=64: 384 active blocks]
  gemm_bt<3, false, true, 64><<<dim3(64, 12), 256, 0, stream>>>(
      h1bf, fc2T, fc2_b, nullptr, eidx, h2, 768, 1536);

  hipMemsetAsync(pooled, 0, (size_t)2 * CDIM * 4, stream);
  pool_partial_kernel<<<dim3(96), 256, 0, stream>>>(h2, edge, pooled);
  eca_kernel<<<dim3(2), 768, 0, stream>>>(pooled, eca_w, cntZ, gate);
  combine_kernel<<<dim3(6144), 256, 0, stream>>>(x, attn, h2, gate, edge, out);
}